// Round 2
// baseline (26.880 us; speedup 1.0000x reference)
//
#include <hip/hip_runtime.h>

// ---------------------------------------------------------------------------
// Lamm loss on MI355X — single fused kernel + 4-byte memset for the ticket.
// Levels (b=64): (100,167) (50,84) (25,42) (13,21) (7,11)
// Blocks [0,171): h-level partial sums (fixed-order, deterministic).
// Blocks [171,176): per-level rasterize+count, whole diff-grid in LDS.
// Last block to finish (device-scope ticket) combines partials -> loss.
// ---------------------------------------------------------------------------

#define NBOXES 4096

__device__ __constant__ int c_LH[5] = {100, 50, 25, 13, 7};
__device__ __constant__ int c_LW[5] = {167, 84, 42, 21, 11};
__device__ __constant__ int c_LS[5] = {167, 85, 43, 21, 11};   // odd LDS stride
__device__ __constant__ int c_LN4[5] = {267200, 67200, 16800, 4368, 1232}; // 64*h*w/4
__device__ __constant__ int c_NBS[5]   = {128, 32, 8, 2, 1};
__device__ __constant__ int c_NBOFF[5] = {0, 128, 160, 168, 170};

#define NB_SUM   171
#define NB_TOTAL 176
#define WS_COV   176           // ws float index for per-level coverage counts
#define CNT_BYTE_OFF 736       // int ticket at ws float index 184

__global__ __launch_bounds__(256) void k_fused(
    const float* __restrict__ h0, const float* __restrict__ h1,
    const float* __restrict__ h2, const float* __restrict__ h3,
    const float* __restrict__ h4, const float* __restrict__ boxes,
    const int* __restrict__ dimx, const int* __restrict__ dimy,
    float* __restrict__ ws, unsigned int* __restrict__ ticket,
    float* __restrict__ out)
{
    __shared__ int   sgrid[16704];   // max level grid h*S = 100*167 (pad to x4)
    __shared__ float fred[256];
    __shared__ float lv5[5];
    __shared__ int   sLast;

    const int bid = blockIdx.x;
    const int tid = threadIdx.x;

    if (bid < NB_SUM) {
        // ------------------ h-level sum reduction ------------------
        int level;
        if      (bid < 128) level = 0;
        else if (bid < 160) level = 1;
        else if (bid < 168) level = 2;
        else if (bid < 170) level = 3;
        else                level = 4;

        const float* hp = (level == 0) ? h0 :
                          (level == 1) ? h1 :
                          (level == 2) ? h2 :
                          (level == 3) ? h3 : h4;
        const int n4   = c_LN4[level];
        const int nb   = c_NBS[level];
        const int boff = c_NBOFF[level];

        const float4* p = (const float4*)hp;
        int idx    = (bid - boff) * 256 + tid;
        int stride = nb * 256;
        float s = 0.0f;
        for (int i = idx; i < n4; i += stride) {
            float4 v = p[i];
            s += v.x + v.y + v.z + v.w;
        }
        fred[tid] = s;
        __syncthreads();
        #pragma unroll
        for (int off = 128; off > 0; off >>= 1) {
            if (tid < off) fred[tid] += fred[tid + off];
            __syncthreads();
        }
        if (tid == 0) ws[bid] = fred[0];
    } else {
        // ------------------ per-level rasterize + count ------------------
        const int level = bid - NB_SUM;
        const int h = c_LH[level];
        const int w = c_LW[level];
        const int S = c_LS[level];
        const int cells = h * S;

        // zero grid with int4 writes
        int4* g4 = (int4*)sgrid;
        const int nz4 = (cells + 3) >> 2;
        for (int i = tid; i < nz4; i += 256) g4[i] = make_int4(0, 0, 0, 0);

        const float sx = (float)((double)w / (double)dimx[0]);
        const float sy = (float)((double)h / (double)dimy[0]);
        __syncthreads();

        const float4* bx = (const float4*)boxes;
        for (int b = tid; b < NBOXES; b += 256) {
            float4 v = bx[b];
            // round (half-even, matches jnp.round) THEN clip, as reference
            int x1 = (int)fminf(fmaxf(rintf(v.x * sx), 0.0f), (float)(w - 1));
            int y1 = (int)fminf(fmaxf(rintf(v.y * sy), 0.0f), (float)(h - 1));
            int x2 = (int)fminf(fmaxf(rintf(v.z * sx), 0.0f), (float)w);
            int y2 = (int)fminf(fmaxf(rintf(v.w * sy), 0.0f), (float)h);
            bool valid = (x2 > x1) && (y2 > y1) && (x1 + x2 < w) && (y1 + y2 < h);
            if (valid) {
                atomicAdd(&sgrid[y1 * S + x1], 1);
                if (x2 < w)           atomicAdd(&sgrid[y1 * S + x2], -1);
                if (y2 < h)           atomicAdd(&sgrid[y2 * S + x1], -1);
                if (x2 < w && y2 < h) atomicAdd(&sgrid[y2 * S + x2], 1);
            }
        }
        __syncthreads();

        // row cumsum along x — chunked so the 8 LDS reads issue independently
        if (tid < h) {
            int run = 0;
            const int base = tid * S;
            int x = 0;
            for (; x + 8 <= w; x += 8) {
                int r0 = sgrid[base+x+0], r1 = sgrid[base+x+1];
                int r2 = sgrid[base+x+2], r3 = sgrid[base+x+3];
                int r4 = sgrid[base+x+4], r5 = sgrid[base+x+5];
                int r6 = sgrid[base+x+6], r7 = sgrid[base+x+7];
                run += r0; sgrid[base+x+0] = run;
                run += r1; sgrid[base+x+1] = run;
                run += r2; sgrid[base+x+2] = run;
                run += r3; sgrid[base+x+3] = run;
                run += r4; sgrid[base+x+4] = run;
                run += r5; sgrid[base+x+5] = run;
                run += r6; sgrid[base+x+6] = run;
                run += r7; sgrid[base+x+7] = run;
            }
            for (; x < w; ++x) { run += sgrid[base + x]; sgrid[base + x] = run; }
        }
        __syncthreads();

        // column cumsum + covered-cell count, chunked
        int cover = 0;
        if (tid < w) {
            int run = 0;
            int y = 0;
            for (; y + 8 <= h; y += 8) {
                int r[8];
                #pragma unroll
                for (int k = 0; k < 8; ++k) r[k] = sgrid[(y + k) * S + tid];
                #pragma unroll
                for (int k = 0; k < 8; ++k) { run += r[k]; cover += (run > 0); }
            }
            for (; y < h; ++y) { run += sgrid[y * S + tid]; cover += (run > 0); }
        }
        fred[tid] = (float)cover;
        __syncthreads();
        #pragma unroll
        for (int off = 128; off > 0; off >>= 1) {
            if (tid < off) fred[tid] += fred[tid + off];
            __syncthreads();
        }
        if (tid == 0) ws[WS_COV + level] = fred[0];
    }

    // ------------------ ticket: last block combines ------------------
    if (tid == 0) {
        __threadfence();
        unsigned int old = atomicAdd(ticket, 1u);
        sLast = (old == NB_TOTAL - 1) ? 1 : 0;
    }
    __syncthreads();
    if (!sLast) return;

    __threadfence();
    volatile float* vws = (volatile float*)ws;
    fred[tid] = (tid < NB_SUM) ? vws[tid] : 0.0f;
    __syncthreads();
    // tree-reduce level-0 partials (fred[0:128]); levels 1-4 stay untouched
    #pragma unroll
    for (int off = 64; off > 0; off >>= 1) {
        if (tid < off) fred[tid] += fred[tid + off];
        __syncthreads();
    }
    if (tid < 5) {
        float s;
        if (tid == 0) s = fred[0];
        else {
            s = 0.0f;
            const int o = c_NBOFF[tid], n = c_NBS[tid];
            for (int i = 0; i < n; ++i) s += fred[o + i];
        }
        const float tn  = (float)(64 * c_LH[tid] * c_LW[tid]);
        const float pi  = vws[WS_COV + tid] / tn;
        const float d   = s / tn - pi;
        lv5[tid] = d * d;
    }
    __syncthreads();
    if (tid == 0)
        out[0] = ((((lv5[0] + lv5[1]) + lv5[2]) + lv5[3]) + lv5[4]) * 0.2f;
}

extern "C" void kernel_launch(void* const* d_in, const int* in_sizes, int n_in,
                              void* d_out, int out_size, void* d_ws, size_t ws_size,
                              hipStream_t stream) {
    const float* h0    = (const float*)d_in[0];
    const float* h1    = (const float*)d_in[1];
    const float* h2    = (const float*)d_in[2];
    const float* h3    = (const float*)d_in[3];
    const float* h4    = (const float*)d_in[4];
    const float* boxes = (const float*)d_in[5];
    const int*   dimx  = (const int*)d_in[6];
    const int*   dimy  = (const int*)d_in[7];
    float* ws  = (float*)d_ws;
    unsigned int* ticket = (unsigned int*)((char*)d_ws + CNT_BYTE_OFF);
    float* out = (float*)d_out;

    hipMemsetAsync(ticket, 0, 4, stream);
    k_fused<<<NB_TOTAL, 256, 0, stream>>>(h0, h1, h2, h3, h4, boxes,
                                          dimx, dimy, ws, ticket, out);
}

// Round 3
// 22.332 us; speedup vs baseline: 1.2037x; 1.2037x over previous
//
#include <hip/hip_runtime.h>

// ---------------------------------------------------------------------------
// Lamm loss on MI355X — ONE kernel node, no memset.
// Blocks [0,171): h-level partial sums (fixed-order, deterministic).
// Blocks [171,176): per-level rasterize+count, whole diff-grid in LDS.
// Block 175 (trivial 7x11 level) is the combiner: it spin-waits on per-block
// done-flags (self-resetting, poison-proof: any value != 1 means not-done,
// flags reset to 0 before kernel exit), then combines partials -> loss.
// ---------------------------------------------------------------------------

#define NBOXES   4096
#define NB_SUM   171
#define NB_TOTAL 176
#define WS_COV   176            // ws float index for per-level coverage counts
#define FLAGS_BYTE_OFF 1024     // 176 uint flags at byte 1024 of ws

__device__ __constant__ int c_LH[5] = {100, 50, 25, 13, 7};
__device__ __constant__ int c_LW[5] = {167, 84, 42, 21, 11};
__device__ __constant__ int c_LS[5] = {167, 85, 43, 21, 11};   // odd LDS stride
__device__ __constant__ int c_LN4[5] = {267200, 67200, 16800, 4368, 1232}; // 64*h*w/4
__device__ __constant__ int c_NBS[5]   = {128, 32, 8, 2, 1};
__device__ __constant__ int c_NBOFF[5] = {0, 128, 160, 168, 170};

__global__ __launch_bounds__(256) void k_fused(
    const float* __restrict__ h0, const float* __restrict__ h1,
    const float* __restrict__ h2, const float* __restrict__ h3,
    const float* __restrict__ h4, const float* __restrict__ boxes,
    const int* __restrict__ dimx, const int* __restrict__ dimy,
    float* __restrict__ ws, unsigned int* __restrict__ flags,
    float* __restrict__ out)
{
    __shared__ int   sgrid[16704];   // max level grid h*S = 100*167 (pad x4)
    __shared__ float fred[256];
    __shared__ float lv5[5];
    __shared__ float cov5[5];

    const int bid = blockIdx.x;
    const int tid = threadIdx.x;
    const bool isComb = (bid == NB_TOTAL - 1);

    if (bid < NB_SUM) {
        // ------------------ h-level sum reduction ------------------
        int level;
        if      (bid < 128) level = 0;
        else if (bid < 160) level = 1;
        else if (bid < 168) level = 2;
        else if (bid < 170) level = 3;
        else                level = 4;

        const float* hp = (level == 0) ? h0 :
                          (level == 1) ? h1 :
                          (level == 2) ? h2 :
                          (level == 3) ? h3 : h4;
        const int n4   = c_LN4[level];
        const int nb   = c_NBS[level];
        const int boff = c_NBOFF[level];

        const float4* p = (const float4*)hp;
        int idx    = (bid - boff) * 256 + tid;
        int stride = nb * 256;
        float s = 0.0f;
        for (int i = idx; i < n4; i += stride) {
            float4 v = p[i];
            s += v.x + v.y + v.z + v.w;
        }
        fred[tid] = s;
        __syncthreads();
        #pragma unroll
        for (int off = 128; off > 0; off >>= 1) {
            if (tid < off) fred[tid] += fred[tid + off];
            __syncthreads();
        }
        if (tid == 0) ws[bid] = fred[0];
    } else {
        // ------------------ per-level rasterize + count ------------------
        const int level = bid - NB_SUM;
        const int h = c_LH[level];
        const int w = c_LW[level];
        const int S = c_LS[level];
        const int cells = h * S;

        int4* g4 = (int4*)sgrid;
        const int nz4 = (cells + 3) >> 2;
        for (int i = tid; i < nz4; i += 256) g4[i] = make_int4(0, 0, 0, 0);

        const float sx = (float)((double)w / (double)dimx[0]);
        const float sy = (float)((double)h / (double)dimy[0]);
        __syncthreads();

        const float4* bx = (const float4*)boxes;
        for (int b = tid; b < NBOXES; b += 256) {
            float4 v = bx[b];
            // round (half-even, matches jnp.round) THEN clip, as reference
            int x1 = (int)fminf(fmaxf(rintf(v.x * sx), 0.0f), (float)(w - 1));
            int y1 = (int)fminf(fmaxf(rintf(v.y * sy), 0.0f), (float)(h - 1));
            int x2 = (int)fminf(fmaxf(rintf(v.z * sx), 0.0f), (float)w);
            int y2 = (int)fminf(fmaxf(rintf(v.w * sy), 0.0f), (float)h);
            bool valid = (x2 > x1) && (y2 > y1) && (x1 + x2 < w) && (y1 + y2 < h);
            if (valid) {
                atomicAdd(&sgrid[y1 * S + x1], 1);
                if (x2 < w)           atomicAdd(&sgrid[y1 * S + x2], -1);
                if (y2 < h)           atomicAdd(&sgrid[y2 * S + x1], -1);
                if (x2 < w && y2 < h) atomicAdd(&sgrid[y2 * S + x2], 1);
            }
        }
        __syncthreads();

        // row cumsum along x — chunked loads break the LDS latency chain
        if (tid < h) {
            int run = 0;
            const int base = tid * S;
            int x = 0;
            for (; x + 8 <= w; x += 8) {
                int r0 = sgrid[base+x+0], r1 = sgrid[base+x+1];
                int r2 = sgrid[base+x+2], r3 = sgrid[base+x+3];
                int r4 = sgrid[base+x+4], r5 = sgrid[base+x+5];
                int r6 = sgrid[base+x+6], r7 = sgrid[base+x+7];
                run += r0; sgrid[base+x+0] = run;
                run += r1; sgrid[base+x+1] = run;
                run += r2; sgrid[base+x+2] = run;
                run += r3; sgrid[base+x+3] = run;
                run += r4; sgrid[base+x+4] = run;
                run += r5; sgrid[base+x+5] = run;
                run += r6; sgrid[base+x+6] = run;
                run += r7; sgrid[base+x+7] = run;
            }
            for (; x < w; ++x) { run += sgrid[base + x]; sgrid[base + x] = run; }
        }
        __syncthreads();

        // column cumsum + covered-cell count, chunked
        int cover = 0;
        if (tid < w) {
            int run = 0;
            int y = 0;
            for (; y + 8 <= h; y += 8) {
                int r[8];
                #pragma unroll
                for (int k = 0; k < 8; ++k) r[k] = sgrid[(y + k) * S + tid];
                #pragma unroll
                for (int k = 0; k < 8; ++k) { run += r[k]; cover += (run > 0); }
            }
            for (; y < h; ++y) { run += sgrid[y * S + tid]; cover += (run > 0); }
        }
        fred[tid] = (float)cover;
        __syncthreads();
        #pragma unroll
        for (int off = 128; off > 0; off >>= 1) {
            if (tid < off) fred[tid] += fred[tid + off];
            __syncthreads();
        }
        if (isComb) {
            if (tid == 0) cov5[4] = fred[0];   // keep own coverage local
        } else {
            if (tid == 0) ws[WS_COV + level] = fred[0];
        }
    }

    // ------------------ signal / combine ------------------
    if (!isComb) {
        if (tid == 0) {
            __threadfence();   // make ws writes visible device-wide
            __hip_atomic_store(&flags[bid], 1u, __ATOMIC_RELEASE,
                               __HIP_MEMORY_SCOPE_AGENT);
        }
        return;
    }

    // combiner: spin on the 175 other blocks' flags (any value != 1 == not
    // done, so poisoned/zeroed initial state is safe), then combine.
    __syncthreads();                 // fred reuse below
    float pv = 0.0f;
    if (tid < NB_SUM) {
        while (__hip_atomic_load(&flags[tid], __ATOMIC_ACQUIRE,
                                 __HIP_MEMORY_SCOPE_AGENT) != 1u)
            __builtin_amdgcn_s_sleep(2);
        pv = __hip_atomic_load(&ws[tid], __ATOMIC_RELAXED,
                               __HIP_MEMORY_SCOPE_AGENT);
    } else if (tid < NB_TOTAL - 1) {
        while (__hip_atomic_load(&flags[tid], __ATOMIC_ACQUIRE,
                                 __HIP_MEMORY_SCOPE_AGENT) != 1u)
            __builtin_amdgcn_s_sleep(2);
        cov5[tid - NB_SUM] = __hip_atomic_load(&ws[WS_COV + (tid - NB_SUM)],
                                               __ATOMIC_RELAXED,
                                               __HIP_MEMORY_SCOPE_AGENT);
    }
    fred[tid] = (tid < NB_SUM) ? pv : 0.0f;
    __syncthreads();
    // tree-reduce level-0 partials (fred[0:128]); fred[128:171] untouched
    #pragma unroll
    for (int off = 64; off > 0; off >>= 1) {
        if (tid < off) fred[tid] += fred[tid + off];
        __syncthreads();
    }
    if (tid < 5) {
        float s;
        if (tid == 0) s = fred[0];
        else {
            s = 0.0f;
            const int o = c_NBOFF[tid], n = c_NBS[tid];
            for (int i = 0; i < n; ++i) s += fred[o + i];
        }
        const float tn = (float)(64 * c_LH[tid] * c_LW[tid]);
        const float pi = cov5[tid] / tn;
        const float d  = s / tn - pi;
        lv5[tid] = d * d;
    }
    __syncthreads();
    if (tid == 0)
        out[0] = ((((lv5[0] + lv5[1]) + lv5[2]) + lv5[3]) + lv5[4]) * 0.2f;

    // reset flags for the next (graph-replayed) call — runs before kernel
    // completion, so the next launch always starts from flags == 0.
    if (tid < NB_TOTAL - 1)
        __hip_atomic_store(&flags[tid], 0u, __ATOMIC_RELAXED,
                           __HIP_MEMORY_SCOPE_AGENT);
}

extern "C" void kernel_launch(void* const* d_in, const int* in_sizes, int n_in,
                              void* d_out, int out_size, void* d_ws, size_t ws_size,
                              hipStream_t stream) {
    const float* h0    = (const float*)d_in[0];
    const float* h1    = (const float*)d_in[1];
    const float* h2    = (const float*)d_in[2];
    const float* h3    = (const float*)d_in[3];
    const float* h4    = (const float*)d_in[4];
    const float* boxes = (const float*)d_in[5];
    const int*   dimx  = (const int*)d_in[6];
    const int*   dimy  = (const int*)d_in[7];
    float* ws  = (float*)d_ws;
    unsigned int* flags = (unsigned int*)((char*)d_ws + FLAGS_BYTE_OFF);
    float* out = (float*)d_out;

    k_fused<<<NB_TOTAL, 256, 0, stream>>>(h0, h1, h2, h3, h4, boxes,
                                          dimx, dimy, ws, flags, out);
}

// Round 4
// 17.987 us; speedup vs baseline: 1.4944x; 1.2415x over previous
//
#include <hip/hip_runtime.h>

// ---------------------------------------------------------------------------
// Lamm loss on MI355X — ONE kernel node, no memset, fence-free handoff.
// Blocks [0,171): h-level partial sums (fixed-order, deterministic).
// Blocks [171,176): per-level rasterize+count, whole diff-grid in LDS.
// Block 175 (trivial 7x11 level) combines. Signalling uses relaxed agent-
// scope atomics (coherent-point, no wbL2/invL2); producer orders data->flag
// with s_waitcnt vmcnt(0) (data completed at coherent point before flag
// issues). Flags are poison-proof (!=1 means not-done) and self-reset.
// ---------------------------------------------------------------------------

#define NBOXES   4096
#define NB_SUM   171
#define NB_TOTAL 176
#define WS_COV   176            // ws uint index for per-level coverage counts
#define FLAGS_BYTE_OFF 1024     // 176 uint flags at byte 1024 of ws

__device__ __constant__ int c_LH[5] = {100, 50, 25, 13, 7};
__device__ __constant__ int c_LW[5] = {167, 84, 42, 21, 11};
__device__ __constant__ int c_LS[5] = {167, 85, 43, 21, 11};   // odd LDS stride
__device__ __constant__ int c_LN4[5] = {267200, 67200, 16800, 4368, 1232}; // 64*h*w/4
__device__ __constant__ int c_NBS[5]   = {128, 32, 8, 2, 1};
__device__ __constant__ int c_NBOFF[5] = {0, 128, 160, 168, 170};

__device__ __forceinline__ void pub_store(unsigned int* p, unsigned int v) {
    __hip_atomic_store(p, v, __ATOMIC_RELAXED, __HIP_MEMORY_SCOPE_AGENT);
}
__device__ __forceinline__ unsigned int pub_load(const unsigned int* p) {
    return __hip_atomic_load(p, __ATOMIC_RELAXED, __HIP_MEMORY_SCOPE_AGENT);
}

__global__ __launch_bounds__(256) void k_fused(
    const float* __restrict__ h0, const float* __restrict__ h1,
    const float* __restrict__ h2, const float* __restrict__ h3,
    const float* __restrict__ h4, const float* __restrict__ boxes,
    const int* __restrict__ dimx, const int* __restrict__ dimy,
    unsigned int* __restrict__ ws, unsigned int* __restrict__ flags,
    float* __restrict__ out)
{
    __shared__ int   sgrid[16704];   // max level grid h*S = 100*167 (pad x4)
    __shared__ float fred[256];
    __shared__ float lv5[5];
    __shared__ float cov5[5];

    const int bid = blockIdx.x;
    const int tid = threadIdx.x;
    const bool isComb = (bid == NB_TOTAL - 1);

    float myPartial = 0.0f;          // value this block publishes

    if (bid < NB_SUM) {
        // ------------------ h-level sum reduction ------------------
        int level;
        if      (bid < 128) level = 0;
        else if (bid < 160) level = 1;
        else if (bid < 168) level = 2;
        else if (bid < 170) level = 3;
        else                level = 4;

        const float* hp = (level == 0) ? h0 :
                          (level == 1) ? h1 :
                          (level == 2) ? h2 :
                          (level == 3) ? h3 : h4;
        const int n4   = c_LN4[level];
        const int nb   = c_NBS[level];
        const int boff = c_NBOFF[level];

        const float4* p = (const float4*)hp;
        int idx    = (bid - boff) * 256 + tid;
        int stride = nb * 256;
        float s = 0.0f;
        for (int i = idx; i < n4; i += stride) {
            float4 v = p[i];
            s += v.x + v.y + v.z + v.w;
        }
        fred[tid] = s;
        __syncthreads();
        #pragma unroll
        for (int off = 128; off > 0; off >>= 1) {
            if (tid < off) fred[tid] += fred[tid + off];
            __syncthreads();
        }
        myPartial = fred[0];
    } else {
        // ------------------ per-level rasterize + count ------------------
        const int level = bid - NB_SUM;
        const int h = c_LH[level];
        const int w = c_LW[level];
        const int S = c_LS[level];
        const int cells = h * S;

        int4* g4 = (int4*)sgrid;
        const int nz4 = (cells + 3) >> 2;
        for (int i = tid; i < nz4; i += 256) g4[i] = make_int4(0, 0, 0, 0);

        const float sx = (float)((double)w / (double)dimx[0]);
        const float sy = (float)((double)h / (double)dimy[0]);
        __syncthreads();

        const float4* bx = (const float4*)boxes;
        for (int b = tid; b < NBOXES; b += 256) {
            float4 v = bx[b];
            // round (half-even, matches jnp.round) THEN clip, as reference
            int x1 = (int)fminf(fmaxf(rintf(v.x * sx), 0.0f), (float)(w - 1));
            int y1 = (int)fminf(fmaxf(rintf(v.y * sy), 0.0f), (float)(h - 1));
            int x2 = (int)fminf(fmaxf(rintf(v.z * sx), 0.0f), (float)w);
            int y2 = (int)fminf(fmaxf(rintf(v.w * sy), 0.0f), (float)h);
            bool valid = (x2 > x1) && (y2 > y1) && (x1 + x2 < w) && (y1 + y2 < h);
            if (valid) {
                atomicAdd(&sgrid[y1 * S + x1], 1);
                if (x2 < w)           atomicAdd(&sgrid[y1 * S + x2], -1);
                if (y2 < h)           atomicAdd(&sgrid[y2 * S + x1], -1);
                if (x2 < w && y2 < h) atomicAdd(&sgrid[y2 * S + x2], 1);
            }
        }
        __syncthreads();

        // row cumsum along x — chunked loads break the LDS latency chain
        if (tid < h) {
            int run = 0;
            const int base = tid * S;
            int x = 0;
            for (; x + 8 <= w; x += 8) {
                int r0 = sgrid[base+x+0], r1 = sgrid[base+x+1];
                int r2 = sgrid[base+x+2], r3 = sgrid[base+x+3];
                int r4 = sgrid[base+x+4], r5 = sgrid[base+x+5];
                int r6 = sgrid[base+x+6], r7 = sgrid[base+x+7];
                run += r0; sgrid[base+x+0] = run;
                run += r1; sgrid[base+x+1] = run;
                run += r2; sgrid[base+x+2] = run;
                run += r3; sgrid[base+x+3] = run;
                run += r4; sgrid[base+x+4] = run;
                run += r5; sgrid[base+x+5] = run;
                run += r6; sgrid[base+x+6] = run;
                run += r7; sgrid[base+x+7] = run;
            }
            for (; x < w; ++x) { run += sgrid[base + x]; sgrid[base + x] = run; }
        }
        __syncthreads();

        // column cumsum + covered-cell count, chunked
        int cover = 0;
        if (tid < w) {
            int run = 0;
            int y = 0;
            for (; y + 8 <= h; y += 8) {
                int r[8];
                #pragma unroll
                for (int k = 0; k < 8; ++k) r[k] = sgrid[(y + k) * S + tid];
                #pragma unroll
                for (int k = 0; k < 8; ++k) { run += r[k]; cover += (run > 0); }
            }
            for (; y < h; ++y) { run += sgrid[y * S + tid]; cover += (run > 0); }
        }
        fred[tid] = (float)cover;
        __syncthreads();
        #pragma unroll
        for (int off = 128; off > 0; off >>= 1) {
            if (tid < off) fred[tid] += fred[tid + off];
            __syncthreads();
        }
        if (isComb) { if (tid == 0) cov5[4] = fred[0]; }
        else        myPartial = fred[0];
    }

    // ------------------ publish (producers) ------------------
    if (!isComb) {
        if (tid == 0) {
            const int slot = (bid < NB_SUM) ? bid : (WS_COV + (bid - NB_SUM));
            pub_store(&ws[slot], __float_as_uint(myPartial));
            asm volatile("s_waitcnt vmcnt(0)" ::: "memory"); // data at coherent pt
            pub_store(&flags[bid], 1u);
        }
        return;
    }

    // ------------------ combiner: spin + combine ------------------
    __syncthreads();                 // fred reuse below
    float pv = 0.0f;
    if (tid < NB_TOTAL - 1) {
        while (pub_load(&flags[tid]) != 1u)
            __builtin_amdgcn_s_sleep(1);
        const int slot = (tid < NB_SUM) ? tid : (WS_COV + (tid - NB_SUM));
        float v = __uint_as_float(pub_load(&ws[slot]));
        if (tid < NB_SUM) pv = v;
        else              cov5[tid - NB_SUM] = v;
    }
    fred[tid] = (tid < NB_SUM) ? pv : 0.0f;
    __syncthreads();
    // tree-reduce level-0 partials (fred[0:128]); fred[128:171] untouched
    #pragma unroll
    for (int off = 64; off > 0; off >>= 1) {
        if (tid < off) fred[tid] += fred[tid + off];
        __syncthreads();
    }
    if (tid < 5) {
        float s;
        if (tid == 0) s = fred[0];
        else {
            s = 0.0f;
            const int o = c_NBOFF[tid], n = c_NBS[tid];
            for (int i = 0; i < n; ++i) s += fred[o + i];
        }
        const float tn = (float)(64 * c_LH[tid] * c_LW[tid]);
        const float pi = cov5[tid] / tn;
        const float d  = s / tn - pi;
        lv5[tid] = d * d;
    }
    __syncthreads();
    if (tid == 0)
        out[0] = ((((lv5[0] + lv5[1]) + lv5[2]) + lv5[3]) + lv5[4]) * 0.2f;

    // reset flags for the next (graph-replayed) call
    if (tid < NB_TOTAL - 1)
        pub_store(&flags[tid], 0u);
}

extern "C" void kernel_launch(void* const* d_in, const int* in_sizes, int n_in,
                              void* d_out, int out_size, void* d_ws, size_t ws_size,
                              hipStream_t stream) {
    const float* h0    = (const float*)d_in[0];
    const float* h1    = (const float*)d_in[1];
    const float* h2    = (const float*)d_in[2];
    const float* h3    = (const float*)d_in[3];
    const float* h4    = (const float*)d_in[4];
    const float* boxes = (const float*)d_in[5];
    const int*   dimx  = (const int*)d_in[6];
    const int*   dimy  = (const int*)d_in[7];
    unsigned int* ws   = (unsigned int*)d_ws;
    unsigned int* flags = (unsigned int*)((char*)d_ws + FLAGS_BYTE_OFF);
    float* out = (float*)d_out;

    k_fused<<<NB_TOTAL, 256, 0, stream>>>(h0, h1, h2, h3, h4, boxes,
                                          dimx, dimy, ws, flags, out);
}

// Round 5
// 16.708 us; speedup vs baseline: 1.6088x; 1.0766x over previous
//
#include <hip/hip_runtime.h>

// ---------------------------------------------------------------------------
// Lamm loss on MI355X — ONE kernel node; raster split into y-bands.
// Blocks [0,171): h-level partial sums (fixed-order, deterministic).
// Blocks [171,180): raster bands: L0 x4 (25 rows), L1 x2 (25), L2, L3, L4.
//   Each band rasterizes boxes y-clipped to its band into a band-local LDS
//   difference grid, does segmented row scan + column scan + count.
//   Band coverages sum to the level coverage (bands are independent).
// Block 179 (L4, trivial) is the combiner: relaxed agent-scope flag spin
// (poison-proof, self-resetting), producer orders data->flag via vmcnt(0).
// ---------------------------------------------------------------------------

#define NBOXES   4096
#define NB_SUM   171
#define NB_TOTAL 180
#define WS_COV   176            // ws uint slots 176..183 = 8 published band covs
#define FLAGS_BYTE_OFF 1024     // uint flags at byte 1024 of ws

__device__ __constant__ int c_LH[5] = {100, 50, 25, 13, 7};
__device__ __constant__ int c_LW[5] = {167, 84, 42, 21, 11};
__device__ __constant__ int c_LS[5] = {167, 85, 43, 21, 11};   // odd LDS stride
__device__ __constant__ int c_LN4[5] = {267200, 67200, 16800, 4368, 1232}; // 64*h*w/4
__device__ __constant__ int c_NBS[5]   = {128, 32, 8, 2, 1};
__device__ __constant__ int c_NBOFF[5] = {0, 128, 160, 168, 170};

// raster band tables: 4 L0 bands, 2 L1 bands, L2, L3, L4(combiner)
__device__ __constant__ int c_RLVL[9] = {0, 0, 0, 0, 1, 1, 2, 3, 4};
__device__ __constant__ int c_RY0 [9] = {0, 25, 50, 75, 0, 25, 0, 0, 0};
__device__ __constant__ int c_RBH [9] = {25, 25, 25, 25, 25, 25, 25, 13, 7};

__device__ __forceinline__ void pub_store(unsigned int* p, unsigned int v) {
    __hip_atomic_store(p, v, __ATOMIC_RELAXED, __HIP_MEMORY_SCOPE_AGENT);
}
__device__ __forceinline__ unsigned int pub_load(const unsigned int* p) {
    return __hip_atomic_load(p, __ATOMIC_RELAXED, __HIP_MEMORY_SCOPE_AGENT);
}

__global__ __launch_bounds__(256) void k_fused(
    const float* __restrict__ h0, const float* __restrict__ h1,
    const float* __restrict__ h2, const float* __restrict__ h3,
    const float* __restrict__ h4, const float* __restrict__ boxes,
    const int* __restrict__ dimx, const int* __restrict__ dimy,
    unsigned int* __restrict__ ws, unsigned int* __restrict__ flags,
    float* __restrict__ out)
{
    __shared__ int   sgrid[4176];    // max band grid 25*167 = 4175 (pad x4)
    __shared__ int   tot[200];       // row-scan segment totals/offsets
    __shared__ float fred[256];
    __shared__ float lv5[5];
    __shared__ float bc[8];          // gathered band coverages (combiner)
    __shared__ float cov4;           // combiner's own (L4) coverage

    const int bid = blockIdx.x;
    const int tid = threadIdx.x;
    const bool isComb = (bid == NB_TOTAL - 1);

    float myPartial = 0.0f;          // value this block publishes

    if (bid < NB_SUM) {
        // ------------------ h-level sum reduction ------------------
        int level;
        if      (bid < 128) level = 0;
        else if (bid < 160) level = 1;
        else if (bid < 168) level = 2;
        else if (bid < 170) level = 3;
        else                level = 4;

        const float* hp = (level == 0) ? h0 :
                          (level == 1) ? h1 :
                          (level == 2) ? h2 :
                          (level == 3) ? h3 : h4;
        const int n4   = c_LN4[level];
        const int nb   = c_NBS[level];
        const int boff = c_NBOFF[level];

        const float4* p = (const float4*)hp;
        int idx    = (bid - boff) * 256 + tid;
        int stride = nb * 256;
        float s = 0.0f;
        for (int i = idx; i < n4; i += stride) {
            float4 v = p[i];
            s += v.x + v.y + v.z + v.w;
        }
        fred[tid] = s;
        __syncthreads();
        #pragma unroll
        for (int off = 128; off > 0; off >>= 1) {
            if (tid < off) fred[tid] += fred[tid + off];
            __syncthreads();
        }
        myPartial = fred[0];
    } else {
        // ------------------ raster band ------------------
        const int rb    = bid - NB_SUM;
        const int level = c_RLVL[rb];
        const int h  = c_LH[level];
        const int w  = c_LW[level];
        const int S  = c_LS[level];
        const int y0 = c_RY0[rb];
        const int bh = c_RBH[rb];
        const int cells = bh * S;

        int4* g4 = (int4*)sgrid;
        const int nz4 = (cells + 3) >> 2;
        for (int i = tid; i < nz4; i += 256) g4[i] = make_int4(0, 0, 0, 0);

        const float sx = (float)((double)w / (double)dimx[0]);
        const float sy = (float)((double)h / (double)dimy[0]);
        __syncthreads();

        const float4* bx = (const float4*)boxes;
        for (int b = tid; b < NBOXES; b += 256) {
            float4 v = bx[b];
            // round (half-even = jnp.round) THEN clip, full-level coords
            int x1 = (int)fminf(fmaxf(rintf(v.x * sx), 0.0f), (float)(w - 1));
            int y1 = (int)fminf(fmaxf(rintf(v.y * sy), 0.0f), (float)(h - 1));
            int x2 = (int)fminf(fmaxf(rintf(v.z * sx), 0.0f), (float)w);
            int y2 = (int)fminf(fmaxf(rintf(v.w * sy), 0.0f), (float)h);
            bool valid = (x2 > x1) && (y2 > y1) && (x1 + x2 < w) && (y1 + y2 < h);
            if (valid) {
                // clip y-interval [y1,y2) to band [y0,y0+bh)
                int r1 = max(y1, y0) - y0;
                int r2 = min(y2, y0 + bh) - y0;
                if (r1 < r2) {
                    atomicAdd(&sgrid[r1 * S + x1], 1);
                    if (x2 < w) atomicAdd(&sgrid[r1 * S + x2], -1);
                    if (r2 < bh) {
                        atomicAdd(&sgrid[r2 * S + x1], -1);
                        if (x2 < w) atomicAdd(&sgrid[r2 * S + x2], 1);
                    }
                }
            }
        }
        __syncthreads();

        // ---- segmented row scan: 8 segs/row, then per-row prefix fixup ----
        const int segw  = (w + 7) >> 3;
        const int ntask = bh << 3;
        if (tid < ntask) {
            const int row = tid >> 3, seg = tid & 7;
            const int xA = seg * segw;
            const int xB = min(w, xA + segw);
            const int base = row * S;
            int run = 0;
            int x = xA;
            for (; x + 8 <= xB; x += 8) {
                int r0=sgrid[base+x  ],r1=sgrid[base+x+1],r2=sgrid[base+x+2],r3=sgrid[base+x+3];
                int r4=sgrid[base+x+4],r5=sgrid[base+x+5],r6=sgrid[base+x+6],r7=sgrid[base+x+7];
                run+=r0; sgrid[base+x  ]=run; run+=r1; sgrid[base+x+1]=run;
                run+=r2; sgrid[base+x+2]=run; run+=r3; sgrid[base+x+3]=run;
                run+=r4; sgrid[base+x+4]=run; run+=r5; sgrid[base+x+5]=run;
                run+=r6; sgrid[base+x+6]=run; run+=r7; sgrid[base+x+7]=run;
            }
            for (; x + 4 <= xB; x += 4) {
                int r0=sgrid[base+x],r1=sgrid[base+x+1],r2=sgrid[base+x+2],r3=sgrid[base+x+3];
                run+=r0; sgrid[base+x  ]=run; run+=r1; sgrid[base+x+1]=run;
                run+=r2; sgrid[base+x+2]=run; run+=r3; sgrid[base+x+3]=run;
            }
            for (; x < xB; ++x) { run += sgrid[base+x]; sgrid[base+x] = run; }
            tot[tid] = run;
        }
        __syncthreads();
        if (tid < bh) {    // exclusive prefix of 8 seg totals, in place
            const int b8 = tid << 3;
            int t0=tot[b8],t1=tot[b8+1],t2=tot[b8+2],t3=tot[b8+3];
            int t4=tot[b8+4],t5=tot[b8+5],t6=tot[b8+6];
            tot[b8] = 0;
            tot[b8+1]=t0; t0+=t1;
            tot[b8+2]=t0; t0+=t2;
            tot[b8+3]=t0; t0+=t3;
            tot[b8+4]=t0; t0+=t4;
            tot[b8+5]=t0; t0+=t5;
            tot[b8+6]=t0; t0+=t6;
            tot[b8+7]=t0;
        }
        __syncthreads();
        if (tid < ntask) {   // fixup: independent RMWs, chunked
            const int off = tot[tid];
            if (off != 0) {
                const int row = tid >> 3, seg = tid & 7;
                const int xA = seg * segw;
                const int xB = min(w, xA + segw);
                const int base = row * S;
                int x = xA;
                for (; x + 8 <= xB; x += 8) {
                    int r0=sgrid[base+x  ],r1=sgrid[base+x+1],r2=sgrid[base+x+2],r3=sgrid[base+x+3];
                    int r4=sgrid[base+x+4],r5=sgrid[base+x+5],r6=sgrid[base+x+6],r7=sgrid[base+x+7];
                    sgrid[base+x  ]=r0+off; sgrid[base+x+1]=r1+off;
                    sgrid[base+x+2]=r2+off; sgrid[base+x+3]=r3+off;
                    sgrid[base+x+4]=r4+off; sgrid[base+x+5]=r5+off;
                    sgrid[base+x+6]=r6+off; sgrid[base+x+7]=r7+off;
                }
                for (; x < xB; ++x) sgrid[base+x] += off;
            }
        }
        __syncthreads();

        // ---- column scan + covered-cell count ----
        int cover = 0;
        if (tid < w) {
            int run = 0;
            int y = 0;
            for (; y + 8 <= bh; y += 8) {
                int r[8];
                #pragma unroll
                for (int k = 0; k < 8; ++k) r[k] = sgrid[(y + k) * S + tid];
                #pragma unroll
                for (int k = 0; k < 8; ++k) { run += r[k]; cover += (run > 0); }
            }
            for (; y + 4 <= bh; y += 4) {
                int r[4];
                #pragma unroll
                for (int k = 0; k < 4; ++k) r[k] = sgrid[(y + k) * S + tid];
                #pragma unroll
                for (int k = 0; k < 4; ++k) { run += r[k]; cover += (run > 0); }
            }
            for (; y < bh; ++y) { run += sgrid[y * S + tid]; cover += (run > 0); }
        }
        fred[tid] = (float)cover;
        __syncthreads();
        #pragma unroll
        for (int off = 128; off > 0; off >>= 1) {
            if (tid < off) fred[tid] += fred[tid + off];
            __syncthreads();
        }
        if (isComb) { if (tid == 0) cov4 = fred[0]; }
        else        myPartial = fred[0];
    }

    // ------------------ publish (producers) ------------------
    if (!isComb) {
        if (tid == 0) {
            const int slot = (bid < NB_SUM) ? bid : (WS_COV + (bid - NB_SUM));
            pub_store(&ws[slot], __float_as_uint(myPartial));
            asm volatile("s_waitcnt vmcnt(0)" ::: "memory"); // data at coherent pt
            pub_store(&flags[bid], 1u);
        }
        return;
    }

    // ------------------ combiner: spin + combine ------------------
    __syncthreads();                 // fred reuse below
    float pv = 0.0f;
    if (tid < NB_TOTAL - 1) {
        while (pub_load(&flags[tid]) != 1u)
            __builtin_amdgcn_s_sleep(1);
        const int slot = (tid < NB_SUM) ? tid : (WS_COV + (tid - NB_SUM));
        float v = __uint_as_float(pub_load(&ws[slot]));
        if (tid < NB_SUM) pv = v;
        else              bc[tid - NB_SUM] = v;
    }
    fred[tid] = (tid < NB_SUM) ? pv : 0.0f;
    __syncthreads();
    // tree-reduce level-0 partials (fred[0:128]); fred[128:171] untouched
    #pragma unroll
    for (int off = 64; off > 0; off >>= 1) {
        if (tid < off) fred[tid] += fred[tid + off];
        __syncthreads();
    }
    if (tid < 5) {
        float s;
        if (tid == 0) s = fred[0];
        else {
            s = 0.0f;
            const int o = c_NBOFF[tid], n = c_NBS[tid];
            for (int i = 0; i < n; ++i) s += fred[o + i];
        }
        float cov;
        if      (tid == 0) cov = bc[0] + bc[1] + bc[2] + bc[3];
        else if (tid == 1) cov = bc[4] + bc[5];
        else if (tid == 2) cov = bc[6];
        else if (tid == 3) cov = bc[7];
        else               cov = cov4;
        const float tn = (float)(64 * c_LH[tid] * c_LW[tid]);
        const float pi = cov / tn;
        const float d  = s / tn - pi;
        lv5[tid] = d * d;
    }
    __syncthreads();
    if (tid == 0)
        out[0] = ((((lv5[0] + lv5[1]) + lv5[2]) + lv5[3]) + lv5[4]) * 0.2f;

    // reset flags for the next (graph-replayed) call
    if (tid < NB_TOTAL - 1)
        pub_store(&flags[tid], 0u);
}

extern "C" void kernel_launch(void* const* d_in, const int* in_sizes, int n_in,
                              void* d_out, int out_size, void* d_ws, size_t ws_size,
                              hipStream_t stream) {
    const float* h0    = (const float*)d_in[0];
    const float* h1    = (const float*)d_in[1];
    const float* h2    = (const float*)d_in[2];
    const float* h3    = (const float*)d_in[3];
    const float* h4    = (const float*)d_in[4];
    const float* boxes = (const float*)d_in[5];
    const int*   dimx  = (const int*)d_in[6];
    const int*   dimy  = (const int*)d_in[7];
    unsigned int* ws   = (unsigned int*)d_ws;
    unsigned int* flags = (unsigned int*)((char*)d_ws + FLAGS_BYTE_OFF);
    float* out = (float*)d_out;

    k_fused<<<NB_TOTAL, 256, 0, stream>>>(h0, h1, h2, h3, h4, boxes,
                                          dimx, dimy, ws, flags, out);
}

// Round 6
// 14.940 us; speedup vs baseline: 1.7992x; 1.1183x over previous
//
#include <hip/hip_runtime.h>

// ---------------------------------------------------------------------------
// Lamm loss on MI355X — ONE kernel node; y-banded raster; packed publish.
// Blocks [0,171): h-level partial sums (shuffle-reduced, deterministic).
// Blocks [171,180): raster bands: L0 x4 (25 rows), L1 x2, L2, L3, L4.
// Publish: ONE 8-byte relaxed agent-scope atomic store {flag=1 | payload}
//   (atomic => no ordering fence needed; poison 0xAA != 1 => safe; combiner
//   resets slots to 0 for the next graph replay).
// Block 179 (L4, trivial) combines: spins on slots, fixed-point LDS-atomic
//   segmented reduce (integer adds commute => deterministic).
// ---------------------------------------------------------------------------

#define NBOXES   4096
#define NB_SUM   171
#define NB_TOTAL 180

__device__ __constant__ int c_LH[5] = {100, 50, 25, 13, 7};
__device__ __constant__ int c_LW[5] = {167, 84, 42, 21, 11};
__device__ __constant__ int c_LS[5] = {167, 85, 43, 21, 11};   // odd LDS stride
__device__ __constant__ int c_LN4[5] = {267200, 67200, 16800, 4368, 1232}; // 64*h*w/4

// raster band tables: 4 L0 bands, 2 L1 bands, L2, L3, L4(combiner)
__device__ __constant__ int c_RLVL[9] = {0, 0, 0, 0, 1, 1, 2, 3, 4};
__device__ __constant__ int c_RY0 [9] = {0, 25, 50, 75, 0, 25, 0, 0, 0};
__device__ __constant__ int c_RBH [9] = {25, 25, 25, 25, 25, 25, 25, 13, 7};

__device__ __forceinline__ void pub_store64(unsigned long long* p, unsigned long long v) {
    __hip_atomic_store(p, v, __ATOMIC_RELAXED, __HIP_MEMORY_SCOPE_AGENT);
}
__device__ __forceinline__ unsigned long long pub_load64(const unsigned long long* p) {
    return __hip_atomic_load(p, __ATOMIC_RELAXED, __HIP_MEMORY_SCOPE_AGENT);
}

__device__ __forceinline__ float wred_f(float s) {
    #pragma unroll
    for (int o = 32; o > 0; o >>= 1) s += __shfl_down(s, o, 64);
    return s;   // valid in lane 0
}
__device__ __forceinline__ int wred_i(int s) {
    #pragma unroll
    for (int o = 32; o > 0; o >>= 1) s += __shfl_down(s, o, 64);
    return s;   // valid in lane 0
}

__global__ __launch_bounds__(256) void k_fused(
    const float* __restrict__ h0, const float* __restrict__ h1,
    const float* __restrict__ h2, const float* __restrict__ h3,
    const float* __restrict__ h4, const float* __restrict__ boxes,
    const int* __restrict__ dimx, const int* __restrict__ dimy,
    unsigned long long* __restrict__ slab, float* __restrict__ out)
{
    __shared__ int   sgrid[4176];    // max band grid 25*167 = 4175 (pad x4)
    __shared__ int   tot[200];       // row-scan segment totals/offsets
    __shared__ float w4f[4];
    __shared__ int   w4i[4];
    __shared__ int   lsum[5];        // fixed-point level h-sums (x256)
    __shared__ int   lcov[5];        // integer level coverage counts
    __shared__ int   cov4i;          // combiner's own (L4) coverage

    const int bid = blockIdx.x;
    const int tid = threadIdx.x;
    const bool isComb = (bid == NB_TOTAL - 1);

    float myPartial = 0.0f;          // value this block publishes

    if (bid < NB_SUM) {
        // ------------------ h-level sum reduction ------------------
        int level;
        if      (bid < 128) level = 0;
        else if (bid < 160) level = 1;
        else if (bid < 168) level = 2;
        else if (bid < 170) level = 3;
        else                level = 4;

        const float* hp = (level == 0) ? h0 :
                          (level == 1) ? h1 :
                          (level == 2) ? h2 :
                          (level == 3) ? h3 : h4;
        const int n4   = c_LN4[level];
        const int nb   = (level==0)?128:(level==1)?32:(level==2)?8:(level==3)?2:1;
        const int boff = (level==0)?0:(level==1)?128:(level==2)?160:(level==3)?168:170;

        const float4* p = (const float4*)hp;
        int idx    = (bid - boff) * 256 + tid;
        int stride = nb * 256;
        float s = 0.0f;
        for (int i = idx; i < n4; i += stride) {
            float4 v = p[i];
            s += v.x + v.y + v.z + v.w;
        }
        float r = wred_f(s);
        if ((tid & 63) == 0) w4f[tid >> 6] = r;
        __syncthreads();
        if (tid == 0) myPartial = (w4f[0] + w4f[1]) + (w4f[2] + w4f[3]);
    } else {
        // ------------------ raster band ------------------
        const int rb    = bid - NB_SUM;
        const int level = c_RLVL[rb];
        const int h  = c_LH[level];
        const int w  = c_LW[level];
        const int S  = c_LS[level];
        const int y0 = c_RY0[rb];
        const int bh = c_RBH[rb];
        const int cells = bh * S;

        int4* g4 = (int4*)sgrid;
        const int nz4 = (cells + 3) >> 2;
        for (int i = tid; i < nz4; i += 256) g4[i] = make_int4(0, 0, 0, 0);

        const float sx = (float)((double)w / (double)dimx[0]);
        const float sy = (float)((double)h / (double)dimy[0]);
        __syncthreads();

        const float4* bx = (const float4*)boxes;
        for (int b = tid; b < NBOXES; b += 256) {
            float4 v = bx[b];
            // round (half-even = jnp.round) THEN clip, full-level coords
            int x1 = (int)fminf(fmaxf(rintf(v.x * sx), 0.0f), (float)(w - 1));
            int y1 = (int)fminf(fmaxf(rintf(v.y * sy), 0.0f), (float)(h - 1));
            int x2 = (int)fminf(fmaxf(rintf(v.z * sx), 0.0f), (float)w);
            int y2 = (int)fminf(fmaxf(rintf(v.w * sy), 0.0f), (float)h);
            bool valid = (x2 > x1) && (y2 > y1) && (x1 + x2 < w) && (y1 + y2 < h);
            if (valid) {
                int r1 = max(y1, y0) - y0;
                int r2 = min(y2, y0 + bh) - y0;
                if (r1 < r2) {
                    atomicAdd(&sgrid[r1 * S + x1], 1);
                    if (x2 < w) atomicAdd(&sgrid[r1 * S + x2], -1);
                    if (r2 < bh) {
                        atomicAdd(&sgrid[r2 * S + x1], -1);
                        if (x2 < w) atomicAdd(&sgrid[r2 * S + x2], 1);
                    }
                }
            }
        }
        __syncthreads();

        // ---- segmented row scan: 8 segs/row, then per-row prefix fixup ----
        const int segw  = (w + 7) >> 3;
        const int ntask = bh << 3;
        if (tid < ntask) {
            const int row = tid >> 3, seg = tid & 7;
            const int xA = seg * segw;
            const int xB = min(w, xA + segw);
            const int base = row * S;
            int run = 0;
            int x = xA;
            for (; x + 8 <= xB; x += 8) {
                int r0=sgrid[base+x  ],r1=sgrid[base+x+1],r2=sgrid[base+x+2],r3=sgrid[base+x+3];
                int r4=sgrid[base+x+4],r5=sgrid[base+x+5],r6=sgrid[base+x+6],r7=sgrid[base+x+7];
                run+=r0; sgrid[base+x  ]=run; run+=r1; sgrid[base+x+1]=run;
                run+=r2; sgrid[base+x+2]=run; run+=r3; sgrid[base+x+3]=run;
                run+=r4; sgrid[base+x+4]=run; run+=r5; sgrid[base+x+5]=run;
                run+=r6; sgrid[base+x+6]=run; run+=r7; sgrid[base+x+7]=run;
            }
            for (; x + 4 <= xB; x += 4) {
                int r0=sgrid[base+x],r1=sgrid[base+x+1],r2=sgrid[base+x+2],r3=sgrid[base+x+3];
                run+=r0; sgrid[base+x  ]=run; run+=r1; sgrid[base+x+1]=run;
                run+=r2; sgrid[base+x+2]=run; run+=r3; sgrid[base+x+3]=run;
            }
            for (; x < xB; ++x) { run += sgrid[base+x]; sgrid[base+x] = run; }
            tot[tid] = run;
        }
        __syncthreads();
        if (tid < bh) {    // exclusive prefix of 8 seg totals, in place
            const int b8 = tid << 3;
            int t0=tot[b8],t1=tot[b8+1],t2=tot[b8+2],t3=tot[b8+3];
            int t4=tot[b8+4],t5=tot[b8+5],t6=tot[b8+6];
            tot[b8] = 0;
            tot[b8+1]=t0; t0+=t1;
            tot[b8+2]=t0; t0+=t2;
            tot[b8+3]=t0; t0+=t3;
            tot[b8+4]=t0; t0+=t4;
            tot[b8+5]=t0; t0+=t5;
            tot[b8+6]=t0; t0+=t6;
            tot[b8+7]=t0;
        }
        __syncthreads();
        if (tid < ntask) {   // fixup: independent RMWs, chunked
            const int off = tot[tid];
            if (off != 0) {
                const int row = tid >> 3, seg = tid & 7;
                const int xA = seg * segw;
                const int xB = min(w, xA + segw);
                const int base = row * S;
                int x = xA;
                for (; x + 8 <= xB; x += 8) {
                    int r0=sgrid[base+x  ],r1=sgrid[base+x+1],r2=sgrid[base+x+2],r3=sgrid[base+x+3];
                    int r4=sgrid[base+x+4],r5=sgrid[base+x+5],r6=sgrid[base+x+6],r7=sgrid[base+x+7];
                    sgrid[base+x  ]=r0+off; sgrid[base+x+1]=r1+off;
                    sgrid[base+x+2]=r2+off; sgrid[base+x+3]=r3+off;
                    sgrid[base+x+4]=r4+off; sgrid[base+x+5]=r5+off;
                    sgrid[base+x+6]=r6+off; sgrid[base+x+7]=r7+off;
                }
                for (; x < xB; ++x) sgrid[base+x] += off;
            }
        }
        __syncthreads();

        // ---- column scan + covered-cell count ----
        int cover = 0;
        if (tid < w) {
            int run = 0;
            int y = 0;
            for (; y + 8 <= bh; y += 8) {
                int r[8];
                #pragma unroll
                for (int k = 0; k < 8; ++k) r[k] = sgrid[(y + k) * S + tid];
                #pragma unroll
                for (int k = 0; k < 8; ++k) { run += r[k]; cover += (run > 0); }
            }
            for (; y + 4 <= bh; y += 4) {
                int r[4];
                #pragma unroll
                for (int k = 0; k < 4; ++k) r[k] = sgrid[(y + k) * S + tid];
                #pragma unroll
                for (int k = 0; k < 4; ++k) { run += r[k]; cover += (run > 0); }
            }
            for (; y < bh; ++y) { run += sgrid[y * S + tid]; cover += (run > 0); }
        }
        int rc = wred_i(cover);
        if ((tid & 63) == 0) w4i[tid >> 6] = rc;
        __syncthreads();
        if (tid == 0) {
            int c = (w4i[0] + w4i[1]) + (w4i[2] + w4i[3]);
            if (isComb) cov4i = c;
            else        myPartial = (float)c;
        }
    }

    // ------------------ publish (producers): single packed atomic ----------
    if (!isComb) {
        if (tid == 0)
            pub_store64(&slab[bid],
                        (1ull << 32) | (unsigned long long)__float_as_uint(myPartial));
        return;
    }

    // ------------------ combiner: spin + fixed-point combine ---------------
    if (tid < 5) { lsum[tid] = 0; lcov[tid] = 0; }
    __syncthreads();   // cov4i (tid0) and zeroed accumulators visible

    float pv = 0.0f;
    if (tid < NB_TOTAL - 1) {
        unsigned long long v;
        while (((v = pub_load64(&slab[tid])) >> 32) != 1ull)
            __builtin_amdgcn_s_sleep(1);
        pv = __uint_as_float((unsigned int)(v & 0xffffffffull));
    }
    if (tid < 128) {
        // level-0 partials: wave pre-reduce, 2 LDS atomics total
        float r = wred_f(pv);
        if ((tid & 63) == 0) atomicAdd(&lsum[0], (int)lrintf(r * 256.0f));
    } else if (tid < NB_SUM) {
        const int lvl = (tid < 160) ? 1 : (tid < 168) ? 2 : (tid < 170) ? 3 : 4;
        atomicAdd(&lsum[lvl], (int)lrintf(pv * 256.0f));
    } else if (tid < NB_TOTAL - 1) {
        atomicAdd(&lcov[c_RLVL[tid - NB_SUM]], (int)pv);
    }
    __syncthreads();

    if (tid == 0) {
        float l = 0.0f;
        #pragma unroll
        for (int lvl = 0; lvl < 5; ++lvl) {
            const float tn  = (float)(64 * c_LH[lvl] * c_LW[lvl]);
            const float s   = (float)lsum[lvl] * (1.0f / 256.0f);
            const float cov = (float)lcov[lvl] + ((lvl == 4) ? (float)cov4i : 0.0f);
            const float d   = s / tn - cov / tn;
            l += d * d;
        }
        out[0] = l * 0.2f;
    }

    // reset slots for the next (graph-replayed) call
    if (tid < NB_TOTAL - 1)
        pub_store64(&slab[tid], 0ull);
}

extern "C" void kernel_launch(void* const* d_in, const int* in_sizes, int n_in,
                              void* d_out, int out_size, void* d_ws, size_t ws_size,
                              hipStream_t stream) {
    const float* h0    = (const float*)d_in[0];
    const float* h1    = (const float*)d_in[1];
    const float* h2    = (const float*)d_in[2];
    const float* h3    = (const float*)d_in[3];
    const float* h4    = (const float*)d_in[4];
    const float* boxes = (const float*)d_in[5];
    const int*   dimx  = (const int*)d_in[6];
    const int*   dimy  = (const int*)d_in[7];
    unsigned long long* slab = (unsigned long long*)d_ws;
    float* out = (float*)d_out;

    k_fused<<<NB_TOTAL, 256, 0, stream>>>(h0, h1, h2, h3, h4, boxes,
                                          dimx, dimy, slab, out);
}

// Round 7
// 12.623 us; speedup vs baseline: 2.1293x; 1.1835x over previous
//
#include <hip/hip_runtime.h>

// ---------------------------------------------------------------------------
// Lamm loss on MI355X — ONE kernel node; 512-thread blocks; fine y-bands.
// Blocks [0,171): h-level partial sums (shuffle-reduced, deterministic).
// Blocks [171,187): raster bands: L0 x8, L1 x4, L2 x2, L3, L4(combiner).
// Publish: ONE 8-byte relaxed agent-scope atomic store {flag=1 | payload}
//   (poison 0xAA != 1 => safe; combiner resets slots for next graph replay).
// Combiner: spins on slots, fixed-point LDS-atomic reduce (deterministic).
// ---------------------------------------------------------------------------

#define NBOXES   4096
#define NB_SUM   171
#define NB_RAS   16
#define NB_TOTAL 187
#define THREADS  512

__device__ __constant__ int c_LH[5] = {100, 50, 25, 13, 7};
__device__ __constant__ int c_LW[5] = {167, 84, 42, 21, 11};
__device__ __constant__ int c_LS[5] = {167, 85, 43, 21, 11};   // odd LDS stride
__device__ __constant__ int c_LN4[5] = {267200, 67200, 16800, 4368, 1232}; // 64*h*w/4

// raster band tables: L0 x8, L1 x4, L2 x2, L3, L4(combiner)
__device__ __constant__ int c_RLVL[16] = {0,0,0,0,0,0,0,0, 1,1,1,1, 2,2, 3, 4};
__device__ __constant__ int c_RY0 [16] = {0,13,26,39,52,64,76,88, 0,13,26,38, 0,13, 0, 0};
__device__ __constant__ int c_RBH [16] = {13,13,13,13,12,12,12,12, 13,13,12,12, 13,12, 13, 7};

__device__ __forceinline__ void pub_store64(unsigned long long* p, unsigned long long v) {
    __hip_atomic_store(p, v, __ATOMIC_RELAXED, __HIP_MEMORY_SCOPE_AGENT);
}
__device__ __forceinline__ unsigned long long pub_load64(const unsigned long long* p) {
    return __hip_atomic_load(p, __ATOMIC_RELAXED, __HIP_MEMORY_SCOPE_AGENT);
}

__device__ __forceinline__ float wred_f(float s) {
    #pragma unroll
    for (int o = 32; o > 0; o >>= 1) s += __shfl_down(s, o, 64);
    return s;   // valid in lane 0
}
__device__ __forceinline__ int wred_i(int s) {
    #pragma unroll
    for (int o = 32; o > 0; o >>= 1) s += __shfl_down(s, o, 64);
    return s;   // valid in lane 0
}

__global__ __launch_bounds__(THREADS) void k_fused(
    const float* __restrict__ h0, const float* __restrict__ h1,
    const float* __restrict__ h2, const float* __restrict__ h3,
    const float* __restrict__ h4, const float* __restrict__ boxes,
    const int* __restrict__ dimx, const int* __restrict__ dimy,
    unsigned long long* __restrict__ slab, float* __restrict__ out)
{
    __shared__ int   sgrid[2172];    // max band grid 13*167 = 2171 (pad x4)
    __shared__ int   tot[112];       // row-scan segment totals/offsets
    __shared__ float w8f[8];
    __shared__ int   w8i[8];
    __shared__ int   lsum[5];        // fixed-point level h-sums (x256)
    __shared__ int   lcov[5];        // integer level coverage counts
    __shared__ int   cov4i;          // combiner's own (L4) coverage

    const int bid = blockIdx.x;
    const int tid = threadIdx.x;
    const bool isComb = (bid == NB_TOTAL - 1);

    float myPartial = 0.0f;          // value this block publishes

    if (bid < NB_SUM) {
        // ------------------ h-level sum reduction ------------------
        int level;
        if      (bid < 128) level = 0;
        else if (bid < 160) level = 1;
        else if (bid < 168) level = 2;
        else if (bid < 170) level = 3;
        else                level = 4;

        const float* hp = (level == 0) ? h0 :
                          (level == 1) ? h1 :
                          (level == 2) ? h2 :
                          (level == 3) ? h3 : h4;
        const int n4   = c_LN4[level];
        const int nb   = (level==0)?128:(level==1)?32:(level==2)?8:(level==3)?2:1;
        const int boff = (level==0)?0:(level==1)?128:(level==2)?160:(level==3)?168:170;

        const float4* p = (const float4*)hp;
        int idx    = (bid - boff) * THREADS + tid;
        int stride = nb * THREADS;
        float s = 0.0f;
        for (int i = idx; i < n4; i += stride) {
            float4 v = p[i];
            s += v.x + v.y + v.z + v.w;
        }
        float r = wred_f(s);
        if ((tid & 63) == 0) w8f[tid >> 6] = r;
        __syncthreads();
        if (tid == 0) {
            float a = ((w8f[0] + w8f[1]) + (w8f[2] + w8f[3]))
                    + ((w8f[4] + w8f[5]) + (w8f[6] + w8f[7]));
            myPartial = a;
        }
    } else {
        // ------------------ raster band ------------------
        const int rb    = bid - NB_SUM;
        const int level = c_RLVL[rb];
        const int h  = c_LH[level];
        const int w  = c_LW[level];
        const int S  = c_LS[level];
        const int y0 = c_RY0[rb];
        const int bh = c_RBH[rb];
        const int cells = bh * S;

        int4* g4 = (int4*)sgrid;
        const int nz4 = (cells + 3) >> 2;
        for (int i = tid; i < nz4; i += THREADS) g4[i] = make_int4(0, 0, 0, 0);

        const float sx = (float)((double)w / (double)dimx[0]);
        const float sy = (float)((double)h / (double)dimy[0]);
        __syncthreads();

        const float4* bx = (const float4*)boxes;
        for (int b = tid; b < NBOXES; b += THREADS) {
            float4 v = bx[b];
            // round (half-even = jnp.round) THEN clip, full-level coords
            int x1 = (int)fminf(fmaxf(rintf(v.x * sx), 0.0f), (float)(w - 1));
            int y1 = (int)fminf(fmaxf(rintf(v.y * sy), 0.0f), (float)(h - 1));
            int x2 = (int)fminf(fmaxf(rintf(v.z * sx), 0.0f), (float)w);
            int y2 = (int)fminf(fmaxf(rintf(v.w * sy), 0.0f), (float)h);
            bool valid = (x2 > x1) && (y2 > y1) && (x1 + x2 < w) && (y1 + y2 < h);
            if (valid) {
                int r1 = max(y1, y0) - y0;
                int r2 = min(y2, y0 + bh) - y0;
                if (r1 < r2) {
                    atomicAdd(&sgrid[r1 * S + x1], 1);
                    if (x2 < w) atomicAdd(&sgrid[r1 * S + x2], -1);
                    if (r2 < bh) {
                        atomicAdd(&sgrid[r2 * S + x1], -1);
                        if (x2 < w) atomicAdd(&sgrid[r2 * S + x2], 1);
                    }
                }
            }
        }
        __syncthreads();

        // ---- segmented row scan: 8 segs/row, then per-row prefix fixup ----
        const int segw  = (w + 7) >> 3;
        const int ntask = bh << 3;
        if (tid < ntask) {
            const int row = tid >> 3, seg = tid & 7;
            const int xA = seg * segw;
            const int xB = min(w, xA + segw);
            const int base = row * S;
            int run = 0;
            int x = xA;
            for (; x + 8 <= xB; x += 8) {
                int r0=sgrid[base+x  ],r1=sgrid[base+x+1],r2=sgrid[base+x+2],r3=sgrid[base+x+3];
                int r4=sgrid[base+x+4],r5=sgrid[base+x+5],r6=sgrid[base+x+6],r7=sgrid[base+x+7];
                run+=r0; sgrid[base+x  ]=run; run+=r1; sgrid[base+x+1]=run;
                run+=r2; sgrid[base+x+2]=run; run+=r3; sgrid[base+x+3]=run;
                run+=r4; sgrid[base+x+4]=run; run+=r5; sgrid[base+x+5]=run;
                run+=r6; sgrid[base+x+6]=run; run+=r7; sgrid[base+x+7]=run;
            }
            for (; x + 4 <= xB; x += 4) {
                int r0=sgrid[base+x],r1=sgrid[base+x+1],r2=sgrid[base+x+2],r3=sgrid[base+x+3];
                run+=r0; sgrid[base+x  ]=run; run+=r1; sgrid[base+x+1]=run;
                run+=r2; sgrid[base+x+2]=run; run+=r3; sgrid[base+x+3]=run;
            }
            for (; x < xB; ++x) { run += sgrid[base+x]; sgrid[base+x] = run; }
            tot[tid] = run;
        }
        __syncthreads();
        if (tid < bh) {    // exclusive prefix of 8 seg totals, in place
            const int b8 = tid << 3;
            int t0=tot[b8],t1=tot[b8+1],t2=tot[b8+2],t3=tot[b8+3];
            int t4=tot[b8+4],t5=tot[b8+5],t6=tot[b8+6];
            tot[b8] = 0;
            tot[b8+1]=t0; t0+=t1;
            tot[b8+2]=t0; t0+=t2;
            tot[b8+3]=t0; t0+=t3;
            tot[b8+4]=t0; t0+=t4;
            tot[b8+5]=t0; t0+=t5;
            tot[b8+6]=t0; t0+=t6;
            tot[b8+7]=t0;
        }
        __syncthreads();
        if (tid < ntask) {   // fixup: independent RMWs, chunked
            const int off = tot[tid];
            if (off != 0) {
                const int row = tid >> 3, seg = tid & 7;
                const int xA = seg * segw;
                const int xB = min(w, xA + segw);
                const int base = row * S;
                int x = xA;
                for (; x + 8 <= xB; x += 8) {
                    int r0=sgrid[base+x  ],r1=sgrid[base+x+1],r2=sgrid[base+x+2],r3=sgrid[base+x+3];
                    int r4=sgrid[base+x+4],r5=sgrid[base+x+5],r6=sgrid[base+x+6],r7=sgrid[base+x+7];
                    sgrid[base+x  ]=r0+off; sgrid[base+x+1]=r1+off;
                    sgrid[base+x+2]=r2+off; sgrid[base+x+3]=r3+off;
                    sgrid[base+x+4]=r4+off; sgrid[base+x+5]=r5+off;
                    sgrid[base+x+6]=r6+off; sgrid[base+x+7]=r7+off;
                }
                for (; x < xB; ++x) sgrid[base+x] += off;
            }
        }
        __syncthreads();

        // ---- column scan + covered-cell count ----
        int cover = 0;
        if (tid < w) {
            int run = 0;
            int y = 0;
            for (; y + 8 <= bh; y += 8) {
                int r[8];
                #pragma unroll
                for (int k = 0; k < 8; ++k) r[k] = sgrid[(y + k) * S + tid];
                #pragma unroll
                for (int k = 0; k < 8; ++k) { run += r[k]; cover += (run > 0); }
            }
            for (; y + 4 <= bh; y += 4) {
                int r[4];
                #pragma unroll
                for (int k = 0; k < 4; ++k) r[k] = sgrid[(y + k) * S + tid];
                #pragma unroll
                for (int k = 0; k < 4; ++k) { run += r[k]; cover += (run > 0); }
            }
            for (; y < bh; ++y) { run += sgrid[y * S + tid]; cover += (run > 0); }
        }
        int rc = wred_i(cover);
        if ((tid & 63) == 0) w8i[tid >> 6] = rc;
        __syncthreads();
        if (tid == 0) {
            int c = ((w8i[0] + w8i[1]) + (w8i[2] + w8i[3]))
                  + ((w8i[4] + w8i[5]) + (w8i[6] + w8i[7]));
            if (isComb) cov4i = c;
            else        myPartial = (float)c;
        }
    }

    // ------------------ publish (producers): single packed atomic ----------
    if (!isComb) {
        if (tid == 0)
            pub_store64(&slab[bid],
                        (1ull << 32) | (unsigned long long)__float_as_uint(myPartial));
        return;
    }

    // ------------------ combiner: spin + fixed-point combine ---------------
    if (tid < 5) { lsum[tid] = 0; lcov[tid] = 0; }
    __syncthreads();   // cov4i (tid0) and zeroed accumulators visible

    float pv = 0.0f;
    if (tid < NB_TOTAL - 1) {
        unsigned long long v;
        while (((v = pub_load64(&slab[tid])) >> 32) != 1ull)
            __builtin_amdgcn_s_sleep(1);
        pv = __uint_as_float((unsigned int)(v & 0xffffffffull));
    }
    if (tid < 128) {
        // level-0 partials: wave pre-reduce, 2 LDS atomics total
        float r = wred_f(pv);
        if ((tid & 63) == 0) atomicAdd(&lsum[0], (int)lrintf(r * 256.0f));
    } else if (tid < NB_SUM) {
        const int lvl = (tid < 160) ? 1 : (tid < 168) ? 2 : (tid < 170) ? 3 : 4;
        atomicAdd(&lsum[lvl], (int)lrintf(pv * 256.0f));
    } else if (tid < NB_TOTAL - 1) {
        atomicAdd(&lcov[c_RLVL[tid - NB_SUM]], (int)pv);
    }
    __syncthreads();

    if (tid == 0) {
        float l = 0.0f;
        #pragma unroll
        for (int lvl = 0; lvl < 5; ++lvl) {
            const float tn  = (float)(64 * c_LH[lvl] * c_LW[lvl]);
            const float s   = (float)lsum[lvl] * (1.0f / 256.0f);
            const float cov = (float)lcov[lvl] + ((lvl == 4) ? (float)cov4i : 0.0f);
            const float d   = s / tn - cov / tn;
            l += d * d;
        }
        out[0] = l * 0.2f;
    }

    // reset slots for the next (graph-replayed) call
    if (tid < NB_TOTAL - 1)
        pub_store64(&slab[tid], 0ull);
}

extern "C" void kernel_launch(void* const* d_in, const int* in_sizes, int n_in,
                              void* d_out, int out_size, void* d_ws, size_t ws_size,
                              hipStream_t stream) {
    const float* h0    = (const float*)d_in[0];
    const float* h1    = (const float*)d_in[1];
    const float* h2    = (const float*)d_in[2];
    const float* h3    = (const float*)d_in[3];
    const float* h4    = (const float*)d_in[4];
    const float* boxes = (const float*)d_in[5];
    const int*   dimx  = (const int*)d_in[6];
    const int*   dimy  = (const int*)d_in[7];
    unsigned long long* slab = (unsigned long long*)d_ws;
    float* out = (float*)d_out;

    k_fused<<<NB_TOTAL, THREADS, 0, stream>>>(h0, h1, h2, h3, h4, boxes,
                                              dimx, dimy, slab, out);
}

// Round 8
// 11.886 us; speedup vs baseline: 2.2615x; 1.0621x over previous
//
#include <hip/hip_runtime.h>

// ---------------------------------------------------------------------------
// Lamm loss on MI355X — ONE kernel node; 512-thread blocks; fine y-bands;
// dedicated work-free combiner; register-prefetched box loads.
// Blocks [0,171): h-level partial sums (shuffle-reduced, deterministic).
// Blocks [171,187): raster bands: L0 x8, L1 x4, L2 x2, L3, L4 (all producers).
// Block 187: combiner only — spins on slots from the start, joins, resets.
// Publish: ONE 8-byte relaxed agent-scope atomic store {flag=1 | payload}
//   (poison 0xAA != 1 => safe; combiner resets slots for next graph replay).
// ---------------------------------------------------------------------------

#define NBOXES   4096
#define NB_SUM   171
#define NB_PROD  187
#define NB_TOTAL 188
#define THREADS  512
#define BPT      8               // boxes per thread = NBOXES / THREADS

__device__ __constant__ int c_LH[5] = {100, 50, 25, 13, 7};
__device__ __constant__ int c_LW[5] = {167, 84, 42, 21, 11};
__device__ __constant__ int c_LS[5] = {167, 85, 43, 21, 11};   // odd LDS stride
__device__ __constant__ int c_LN4[5] = {267200, 67200, 16800, 4368, 1232}; // 64*h*w/4

// raster band tables: L0 x8, L1 x4, L2 x2, L3, L4
__device__ __constant__ int c_RLVL[16] = {0,0,0,0,0,0,0,0, 1,1,1,1, 2,2, 3, 4};
__device__ __constant__ int c_RY0 [16] = {0,13,26,39,52,64,76,88, 0,13,26,38, 0,13, 0, 0};
__device__ __constant__ int c_RBH [16] = {13,13,13,13,12,12,12,12, 13,13,12,12, 13,12, 13, 7};

__device__ __forceinline__ void pub_store64(unsigned long long* p, unsigned long long v) {
    __hip_atomic_store(p, v, __ATOMIC_RELAXED, __HIP_MEMORY_SCOPE_AGENT);
}
__device__ __forceinline__ unsigned long long pub_load64(const unsigned long long* p) {
    return __hip_atomic_load(p, __ATOMIC_RELAXED, __HIP_MEMORY_SCOPE_AGENT);
}

__device__ __forceinline__ float wred_f(float s) {
    #pragma unroll
    for (int o = 32; o > 0; o >>= 1) s += __shfl_down(s, o, 64);
    return s;   // valid in lane 0
}
__device__ __forceinline__ int wred_i(int s) {
    #pragma unroll
    for (int o = 32; o > 0; o >>= 1) s += __shfl_down(s, o, 64);
    return s;   // valid in lane 0
}

__global__ __launch_bounds__(THREADS) void k_fused(
    const float* __restrict__ h0, const float* __restrict__ h1,
    const float* __restrict__ h2, const float* __restrict__ h3,
    const float* __restrict__ h4, const float* __restrict__ boxes,
    const int* __restrict__ dimx, const int* __restrict__ dimy,
    unsigned long long* __restrict__ slab, float* __restrict__ out)
{
    __shared__ int   sgrid[2172];    // max band grid 13*167 = 2171 (pad x4)
    __shared__ int   tot[112];       // row-scan segment totals/offsets
    __shared__ float w8f[8];
    __shared__ int   w8i[8];
    __shared__ int   lsum[5];        // fixed-point level h-sums (x256)
    __shared__ int   lcov[5];        // integer level coverage counts

    const int bid = blockIdx.x;
    const int tid = threadIdx.x;

    float myPartial = 0.0f;          // value this block publishes

    if (bid < NB_SUM) {
        // ------------------ h-level sum reduction ------------------
        int level;
        if      (bid < 128) level = 0;
        else if (bid < 160) level = 1;
        else if (bid < 168) level = 2;
        else if (bid < 170) level = 3;
        else                level = 4;

        const float* hp = (level == 0) ? h0 :
                          (level == 1) ? h1 :
                          (level == 2) ? h2 :
                          (level == 3) ? h3 : h4;
        const int n4   = c_LN4[level];
        const int nb   = (level==0)?128:(level==1)?32:(level==2)?8:(level==3)?2:1;
        const int boff = (level==0)?0:(level==1)?128:(level==2)?160:(level==3)?168:170;

        const float4* p = (const float4*)hp;
        int idx    = (bid - boff) * THREADS + tid;
        int stride = nb * THREADS;
        float s = 0.0f;
        for (int i = idx; i < n4; i += stride) {
            float4 v = p[i];
            s += v.x + v.y + v.z + v.w;
        }
        float r = wred_f(s);
        if ((tid & 63) == 0) w8f[tid >> 6] = r;
        __syncthreads();
        if (tid == 0)
            myPartial = ((w8f[0] + w8f[1]) + (w8f[2] + w8f[3]))
                      + ((w8f[4] + w8f[5]) + (w8f[6] + w8f[7]));
    } else if (bid < NB_PROD) {
        // ------------------ raster band ------------------
        const int rb    = bid - NB_SUM;
        const int level = c_RLVL[rb];
        const int h  = c_LH[level];
        const int w  = c_LW[level];
        const int S  = c_LS[level];
        const int y0 = c_RY0[rb];
        const int bh = c_RBH[rb];
        const int cells = bh * S;

        // issue box loads + scale loads FIRST (T14: latency hides under zero)
        const float4* bx = (const float4*)boxes;
        float4 bv[BPT];
        #pragma unroll
        for (int k = 0; k < BPT; ++k) bv[k] = bx[tid + k * THREADS];
        const int dx = dimx[0], dy = dimy[0];

        // zero grid while loads are in flight
        int4* g4 = (int4*)sgrid;
        const int nz4 = (cells + 3) >> 2;
        for (int i = tid; i < nz4; i += THREADS) g4[i] = make_int4(0, 0, 0, 0);

        const float sx = (float)((double)w / (double)dx);
        const float sy = (float)((double)h / (double)dy);
        __syncthreads();

        #pragma unroll
        for (int k = 0; k < BPT; ++k) {
            float4 v = bv[k];
            // round (half-even = jnp.round) THEN clip, full-level coords
            int x1 = (int)fminf(fmaxf(rintf(v.x * sx), 0.0f), (float)(w - 1));
            int y1 = (int)fminf(fmaxf(rintf(v.y * sy), 0.0f), (float)(h - 1));
            int x2 = (int)fminf(fmaxf(rintf(v.z * sx), 0.0f), (float)w);
            int y2 = (int)fminf(fmaxf(rintf(v.w * sy), 0.0f), (float)h);
            bool valid = (x2 > x1) && (y2 > y1) && (x1 + x2 < w) && (y1 + y2 < h);
            if (valid) {
                int r1 = max(y1, y0) - y0;
                int r2 = min(y2, y0 + bh) - y0;
                if (r1 < r2) {
                    atomicAdd(&sgrid[r1 * S + x1], 1);
                    if (x2 < w) atomicAdd(&sgrid[r1 * S + x2], -1);
                    if (r2 < bh) {
                        atomicAdd(&sgrid[r2 * S + x1], -1);
                        if (x2 < w) atomicAdd(&sgrid[r2 * S + x2], 1);
                    }
                }
            }
        }
        __syncthreads();

        // ---- segmented row scan: 8 segs/row, then per-row prefix fixup ----
        const int segw  = (w + 7) >> 3;
        const int ntask = bh << 3;
        if (tid < ntask) {
            const int row = tid >> 3, seg = tid & 7;
            const int xA = seg * segw;
            const int xB = min(w, xA + segw);
            const int base = row * S;
            int run = 0;
            int x = xA;
            for (; x + 8 <= xB; x += 8) {
                int r0=sgrid[base+x  ],r1=sgrid[base+x+1],r2=sgrid[base+x+2],r3=sgrid[base+x+3];
                int r4=sgrid[base+x+4],r5=sgrid[base+x+5],r6=sgrid[base+x+6],r7=sgrid[base+x+7];
                run+=r0; sgrid[base+x  ]=run; run+=r1; sgrid[base+x+1]=run;
                run+=r2; sgrid[base+x+2]=run; run+=r3; sgrid[base+x+3]=run;
                run+=r4; sgrid[base+x+4]=run; run+=r5; sgrid[base+x+5]=run;
                run+=r6; sgrid[base+x+6]=run; run+=r7; sgrid[base+x+7]=run;
            }
            for (; x + 4 <= xB; x += 4) {
                int r0=sgrid[base+x],r1=sgrid[base+x+1],r2=sgrid[base+x+2],r3=sgrid[base+x+3];
                run+=r0; sgrid[base+x  ]=run; run+=r1; sgrid[base+x+1]=run;
                run+=r2; sgrid[base+x+2]=run; run+=r3; sgrid[base+x+3]=run;
            }
            for (; x < xB; ++x) { run += sgrid[base+x]; sgrid[base+x] = run; }
            tot[tid] = run;
        }
        __syncthreads();
        if (tid < bh) {    // exclusive prefix of 8 seg totals, in place
            const int b8 = tid << 3;
            int t0=tot[b8],t1=tot[b8+1],t2=tot[b8+2],t3=tot[b8+3];
            int t4=tot[b8+4],t5=tot[b8+5],t6=tot[b8+6];
            tot[b8] = 0;
            tot[b8+1]=t0; t0+=t1;
            tot[b8+2]=t0; t0+=t2;
            tot[b8+3]=t0; t0+=t3;
            tot[b8+4]=t0; t0+=t4;
            tot[b8+5]=t0; t0+=t5;
            tot[b8+6]=t0; t0+=t6;
            tot[b8+7]=t0;
        }
        __syncthreads();
        if (tid < ntask) {   // fixup: independent RMWs, chunked
            const int off = tot[tid];
            if (off != 0) {
                const int row = tid >> 3, seg = tid & 7;
                const int xA = seg * segw;
                const int xB = min(w, xA + segw);
                const int base = row * S;
                int x = xA;
                for (; x + 8 <= xB; x += 8) {
                    int r0=sgrid[base+x  ],r1=sgrid[base+x+1],r2=sgrid[base+x+2],r3=sgrid[base+x+3];
                    int r4=sgrid[base+x+4],r5=sgrid[base+x+5],r6=sgrid[base+x+6],r7=sgrid[base+x+7];
                    sgrid[base+x  ]=r0+off; sgrid[base+x+1]=r1+off;
                    sgrid[base+x+2]=r2+off; sgrid[base+x+3]=r3+off;
                    sgrid[base+x+4]=r4+off; sgrid[base+x+5]=r5+off;
                    sgrid[base+x+6]=r6+off; sgrid[base+x+7]=r7+off;
                }
                for (; x < xB; ++x) sgrid[base+x] += off;
            }
        }
        __syncthreads();

        // ---- column scan + covered-cell count ----
        int cover = 0;
        if (tid < w) {
            int run = 0;
            int y = 0;
            for (; y + 8 <= bh; y += 8) {
                int r[8];
                #pragma unroll
                for (int k = 0; k < 8; ++k) r[k] = sgrid[(y + k) * S + tid];
                #pragma unroll
                for (int k = 0; k < 8; ++k) { run += r[k]; cover += (run > 0); }
            }
            for (; y + 4 <= bh; y += 4) {
                int r[4];
                #pragma unroll
                for (int k = 0; k < 4; ++k) r[k] = sgrid[(y + k) * S + tid];
                #pragma unroll
                for (int k = 0; k < 4; ++k) { run += r[k]; cover += (run > 0); }
            }
            for (; y < bh; ++y) { run += sgrid[y * S + tid]; cover += (run > 0); }
        }
        int rc = wred_i(cover);
        if ((tid & 63) == 0) w8i[tid >> 6] = rc;
        __syncthreads();
        if (tid == 0)
            myPartial = (float)(((w8i[0] + w8i[1]) + (w8i[2] + w8i[3]))
                              + ((w8i[4] + w8i[5]) + (w8i[6] + w8i[7])));
    }

    // ------------------ publish (producers): single packed atomic ----------
    if (bid < NB_PROD) {
        if (tid == 0)
            pub_store64(&slab[bid],
                        (1ull << 32) | (unsigned long long)__float_as_uint(myPartial));
        return;
    }

    // ------------------ combiner (block 187): spin + fixed-point combine ---
    if (tid < 5) { lsum[tid] = 0; lcov[tid] = 0; }
    __syncthreads();

    float pv = 0.0f;
    if (tid < NB_PROD) {
        unsigned long long v;
        while (((v = pub_load64(&slab[tid])) >> 32) != 1ull)
            __builtin_amdgcn_s_sleep(1);
        pv = __uint_as_float((unsigned int)(v & 0xffffffffull));
    }
    if (tid < 128) {
        // level-0 partials: wave pre-reduce, 2 LDS atomics total
        float r = wred_f(pv);
        if ((tid & 63) == 0) atomicAdd(&lsum[0], (int)lrintf(r * 256.0f));
    } else if (tid < NB_SUM) {
        const int lvl = (tid < 160) ? 1 : (tid < 168) ? 2 : (tid < 170) ? 3 : 4;
        atomicAdd(&lsum[lvl], (int)lrintf(pv * 256.0f));
    } else if (tid < NB_PROD) {
        atomicAdd(&lcov[c_RLVL[tid - NB_SUM]], (int)pv);
    }
    __syncthreads();

    if (tid == 0) {
        float l = 0.0f;
        #pragma unroll
        for (int lvl = 0; lvl < 5; ++lvl) {
            const float tn  = (float)(64 * c_LH[lvl] * c_LW[lvl]);
            const float s   = (float)lsum[lvl] * (1.0f / 256.0f);
            const float cov = (float)lcov[lvl];
            const float d   = s / tn - cov / tn;
            l += d * d;
        }
        out[0] = l * 0.2f;
    }

    // reset slots for the next (graph-replayed) call
    if (tid < NB_PROD)
        pub_store64(&slab[tid], 0ull);
}

extern "C" void kernel_launch(void* const* d_in, const int* in_sizes, int n_in,
                              void* d_out, int out_size, void* d_ws, size_t ws_size,
                              hipStream_t stream) {
    const float* h0    = (const float*)d_in[0];
    const float* h1    = (const float*)d_in[1];
    const float* h2    = (const float*)d_in[2];
    const float* h3    = (const float*)d_in[3];
    const float* h4    = (const float*)d_in[4];
    const float* boxes = (const float*)d_in[5];
    const int*   dimx  = (const int*)d_in[6];
    const int*   dimy  = (const int*)d_in[7];
    unsigned long long* slab = (unsigned long long*)d_ws;
    float* out = (float*)d_out;

    k_fused<<<NB_TOTAL, THREADS, 0, stream>>>(h0, h1, h2, h3, h4, boxes,
                                              dimx, dimy, slab, out);
}

// Round 9
// 11.335 us; speedup vs baseline: 2.3715x; 1.0486x over previous
//
#include <hip/hip_runtime.h>

// ---------------------------------------------------------------------------
// Lamm loss on MI355X — ONE kernel node; 1024-thread blocks; fine y-bands;
// dedicated work-free combiner; register-prefetched box loads.
// Blocks [0,171): h-level partial sums (shuffle-reduced, deterministic).
// Blocks [171,187): raster bands: L0 x8, L1 x4, L2 x2, L3, L4 (all producers).
// Block 187: combiner only — spins on slots from the start, joins, resets.
// Publish: ONE 8-byte relaxed agent-scope atomic store {flag=1 | payload}
//   (poison 0xAA != 1 => safe; combiner resets slots for next graph replay).
// ---------------------------------------------------------------------------

#define NBOXES   4096
#define NB_SUM   171
#define NB_PROD  187
#define NB_TOTAL 188
#define THREADS  1024
#define BPT      4               // boxes per thread = NBOXES / THREADS

__device__ __constant__ int c_LH[5] = {100, 50, 25, 13, 7};
__device__ __constant__ int c_LW[5] = {167, 84, 42, 21, 11};
__device__ __constant__ int c_LS[5] = {167, 85, 43, 21, 11};   // odd LDS stride
__device__ __constant__ int c_LN4[5] = {267200, 67200, 16800, 4368, 1232}; // 64*h*w/4

// raster band tables: L0 x8, L1 x4, L2 x2, L3, L4
__device__ __constant__ int c_RLVL[16] = {0,0,0,0,0,0,0,0, 1,1,1,1, 2,2, 3, 4};
__device__ __constant__ int c_RY0 [16] = {0,13,26,39,52,64,76,88, 0,13,26,38, 0,13, 0, 0};
__device__ __constant__ int c_RBH [16] = {13,13,13,13,12,12,12,12, 13,13,12,12, 13,12, 13, 7};

__device__ __forceinline__ void pub_store64(unsigned long long* p, unsigned long long v) {
    __hip_atomic_store(p, v, __ATOMIC_RELAXED, __HIP_MEMORY_SCOPE_AGENT);
}
__device__ __forceinline__ unsigned long long pub_load64(const unsigned long long* p) {
    return __hip_atomic_load(p, __ATOMIC_RELAXED, __HIP_MEMORY_SCOPE_AGENT);
}

__device__ __forceinline__ float wred_f(float s) {
    #pragma unroll
    for (int o = 32; o > 0; o >>= 1) s += __shfl_down(s, o, 64);
    return s;   // valid in lane 0
}
__device__ __forceinline__ int wred_i(int s) {
    #pragma unroll
    for (int o = 32; o > 0; o >>= 1) s += __shfl_down(s, o, 64);
    return s;   // valid in lane 0
}

__global__ __launch_bounds__(THREADS) void k_fused(
    const float* __restrict__ h0, const float* __restrict__ h1,
    const float* __restrict__ h2, const float* __restrict__ h3,
    const float* __restrict__ h4, const float* __restrict__ boxes,
    const int* __restrict__ dimx, const int* __restrict__ dimy,
    unsigned long long* __restrict__ slab, float* __restrict__ out)
{
    __shared__ int   sgrid[2172];    // max band grid 13*167 = 2171 (pad x4)
    __shared__ int   tot[112];       // row-scan segment totals/offsets
    __shared__ float w16f[16];
    __shared__ int   w16i[16];
    __shared__ int   lsum[5];        // fixed-point level h-sums (x256)
    __shared__ int   lcov[5];        // integer level coverage counts

    const int bid = blockIdx.x;
    const int tid = threadIdx.x;

    float myPartial = 0.0f;          // value this block publishes

    if (bid < NB_SUM) {
        // ------------------ h-level sum reduction ------------------
        int level;
        if      (bid < 128) level = 0;
        else if (bid < 160) level = 1;
        else if (bid < 168) level = 2;
        else if (bid < 170) level = 3;
        else                level = 4;

        const float* hp = (level == 0) ? h0 :
                          (level == 1) ? h1 :
                          (level == 2) ? h2 :
                          (level == 3) ? h3 : h4;
        const int n4   = c_LN4[level];
        const int nb   = (level==0)?128:(level==1)?32:(level==2)?8:(level==3)?2:1;
        const int boff = (level==0)?0:(level==1)?128:(level==2)?160:(level==3)?168:170;

        const float4* p = (const float4*)hp;
        int idx    = (bid - boff) * THREADS + tid;
        int stride = nb * THREADS;
        float s = 0.0f;
        for (int i = idx; i < n4; i += stride) {
            float4 v = p[i];
            s += v.x + v.y + v.z + v.w;
        }
        float r = wred_f(s);
        if ((tid & 63) == 0) w16f[tid >> 6] = r;
        __syncthreads();
        if (tid == 0) {
            float a = 0.0f;
            #pragma unroll
            for (int k = 0; k < 16; ++k) a += w16f[k];
            myPartial = a;
        }
    } else if (bid < NB_PROD) {
        // ------------------ raster band ------------------
        const int rb    = bid - NB_SUM;
        const int level = c_RLVL[rb];
        const int h  = c_LH[level];
        const int w  = c_LW[level];
        const int S  = c_LS[level];
        const int y0 = c_RY0[rb];
        const int bh = c_RBH[rb];
        const int cells = bh * S;

        // issue box loads + dim loads FIRST (latency hides under LDS zero)
        const float4* bx = (const float4*)boxes;
        float4 bv[BPT];
        #pragma unroll
        for (int k = 0; k < BPT; ++k) bv[k] = bx[tid + k * THREADS];
        const int dx = dimx[0], dy = dimy[0];

        // zero grid while loads are in flight
        int4* g4 = (int4*)sgrid;
        const int nz4 = (cells + 3) >> 2;
        for (int i = tid; i < nz4; i += THREADS) g4[i] = make_int4(0, 0, 0, 0);

        const float sx = (float)((double)w / (double)dx);
        const float sy = (float)((double)h / (double)dy);
        __syncthreads();

        #pragma unroll
        for (int k = 0; k < BPT; ++k) {
            float4 v = bv[k];
            // round (half-even = jnp.round) THEN clip, full-level coords
            int x1 = (int)fminf(fmaxf(rintf(v.x * sx), 0.0f), (float)(w - 1));
            int y1 = (int)fminf(fmaxf(rintf(v.y * sy), 0.0f), (float)(h - 1));
            int x2 = (int)fminf(fmaxf(rintf(v.z * sx), 0.0f), (float)w);
            int y2 = (int)fminf(fmaxf(rintf(v.w * sy), 0.0f), (float)h);
            bool valid = (x2 > x1) && (y2 > y1) && (x1 + x2 < w) && (y1 + y2 < h);
            if (valid) {
                int r1 = max(y1, y0) - y0;
                int r2 = min(y2, y0 + bh) - y0;
                if (r1 < r2) {
                    atomicAdd(&sgrid[r1 * S + x1], 1);
                    if (x2 < w) atomicAdd(&sgrid[r1 * S + x2], -1);
                    if (r2 < bh) {
                        atomicAdd(&sgrid[r2 * S + x1], -1);
                        if (x2 < w) atomicAdd(&sgrid[r2 * S + x2], 1);
                    }
                }
            }
        }
        __syncthreads();

        // ---- segmented row scan: 8 segs/row, then per-row prefix fixup ----
        const int segw  = (w + 7) >> 3;
        const int ntask = bh << 3;
        if (tid < ntask) {
            const int row = tid >> 3, seg = tid & 7;
            const int xA = seg * segw;
            const int xB = min(w, xA + segw);
            const int base = row * S;
            int run = 0;
            int x = xA;
            for (; x + 8 <= xB; x += 8) {
                int r0=sgrid[base+x  ],r1=sgrid[base+x+1],r2=sgrid[base+x+2],r3=sgrid[base+x+3];
                int r4=sgrid[base+x+4],r5=sgrid[base+x+5],r6=sgrid[base+x+6],r7=sgrid[base+x+7];
                run+=r0; sgrid[base+x  ]=run; run+=r1; sgrid[base+x+1]=run;
                run+=r2; sgrid[base+x+2]=run; run+=r3; sgrid[base+x+3]=run;
                run+=r4; sgrid[base+x+4]=run; run+=r5; sgrid[base+x+5]=run;
                run+=r6; sgrid[base+x+6]=run; run+=r7; sgrid[base+x+7]=run;
            }
            for (; x + 4 <= xB; x += 4) {
                int r0=sgrid[base+x],r1=sgrid[base+x+1],r2=sgrid[base+x+2],r3=sgrid[base+x+3];
                run+=r0; sgrid[base+x  ]=run; run+=r1; sgrid[base+x+1]=run;
                run+=r2; sgrid[base+x+2]=run; run+=r3; sgrid[base+x+3]=run;
            }
            for (; x < xB; ++x) { run += sgrid[base+x]; sgrid[base+x] = run; }
            tot[tid] = run;
        }
        __syncthreads();
        if (tid < bh) {    // exclusive prefix of 8 seg totals, in place
            const int b8 = tid << 3;
            int t0=tot[b8],t1=tot[b8+1],t2=tot[b8+2],t3=tot[b8+3];
            int t4=tot[b8+4],t5=tot[b8+5],t6=tot[b8+6];
            tot[b8] = 0;
            tot[b8+1]=t0; t0+=t1;
            tot[b8+2]=t0; t0+=t2;
            tot[b8+3]=t0; t0+=t3;
            tot[b8+4]=t0; t0+=t4;
            tot[b8+5]=t0; t0+=t5;
            tot[b8+6]=t0; t0+=t6;
            tot[b8+7]=t0;
        }
        __syncthreads();
        if (tid < ntask) {   // fixup: independent RMWs, chunked
            const int off = tot[tid];
            if (off != 0) {
                const int row = tid >> 3, seg = tid & 7;
                const int xA = seg * segw;
                const int xB = min(w, xA + segw);
                const int base = row * S;
                int x = xA;
                for (; x + 8 <= xB; x += 8) {
                    int r0=sgrid[base+x  ],r1=sgrid[base+x+1],r2=sgrid[base+x+2],r3=sgrid[base+x+3];
                    int r4=sgrid[base+x+4],r5=sgrid[base+x+5],r6=sgrid[base+x+6],r7=sgrid[base+x+7];
                    sgrid[base+x  ]=r0+off; sgrid[base+x+1]=r1+off;
                    sgrid[base+x+2]=r2+off; sgrid[base+x+3]=r3+off;
                    sgrid[base+x+4]=r4+off; sgrid[base+x+5]=r5+off;
                    sgrid[base+x+6]=r6+off; sgrid[base+x+7]=r7+off;
                }
                for (; x < xB; ++x) sgrid[base+x] += off;
            }
        }
        __syncthreads();

        // ---- column scan + covered-cell count ----
        int cover = 0;
        if (tid < w) {
            int run = 0;
            int y = 0;
            for (; y + 8 <= bh; y += 8) {
                int r[8];
                #pragma unroll
                for (int k = 0; k < 8; ++k) r[k] = sgrid[(y + k) * S + tid];
                #pragma unroll
                for (int k = 0; k < 8; ++k) { run += r[k]; cover += (run > 0); }
            }
            for (; y + 4 <= bh; y += 4) {
                int r[4];
                #pragma unroll
                for (int k = 0; k < 4; ++k) r[k] = sgrid[(y + k) * S + tid];
                #pragma unroll
                for (int k = 0; k < 4; ++k) { run += r[k]; cover += (run > 0); }
            }
            for (; y < bh; ++y) { run += sgrid[y * S + tid]; cover += (run > 0); }
        }
        int rc = wred_i(cover);
        if ((tid & 63) == 0) w16i[tid >> 6] = rc;
        __syncthreads();
        if (tid == 0) {
            int c = 0;
            #pragma unroll
            for (int k = 0; k < 16; ++k) c += w16i[k];
            myPartial = (float)c;
        }
    }

    // ------------------ publish (producers): single packed atomic ----------
    if (bid < NB_PROD) {
        if (tid == 0)
            pub_store64(&slab[bid],
                        (1ull << 32) | (unsigned long long)__float_as_uint(myPartial));
        return;
    }

    // ------------------ combiner (block 187): spin + fixed-point combine ---
    if (tid < 5) { lsum[tid] = 0; lcov[tid] = 0; }
    __syncthreads();

    float pv = 0.0f;
    if (tid < NB_PROD) {
        unsigned long long v;
        while (((v = pub_load64(&slab[tid])) >> 32) != 1ull)
            __builtin_amdgcn_s_sleep(1);
        pv = __uint_as_float((unsigned int)(v & 0xffffffffull));
    }
    if (tid < 128) {
        // level-0 partials: wave pre-reduce, 2 LDS atomics total
        float r = wred_f(pv);
        if ((tid & 63) == 0) atomicAdd(&lsum[0], (int)lrintf(r * 256.0f));
    } else if (tid < NB_SUM) {
        const int lvl = (tid < 160) ? 1 : (tid < 168) ? 2 : (tid < 170) ? 3 : 4;
        atomicAdd(&lsum[lvl], (int)lrintf(pv * 256.0f));
    } else if (tid < NB_PROD) {
        atomicAdd(&lcov[c_RLVL[tid - NB_SUM]], (int)pv);
    }
    __syncthreads();

    if (tid == 0) {
        float l = 0.0f;
        #pragma unroll
        for (int lvl = 0; lvl < 5; ++lvl) {
            const float tn  = (float)(64 * c_LH[lvl] * c_LW[lvl]);
            const float s   = (float)lsum[lvl] * (1.0f / 256.0f);
            const float cov = (float)lcov[lvl];
            const float d   = s / tn - cov / tn;
            l += d * d;
        }
        out[0] = l * 0.2f;
    }

    // reset slots for the next (graph-replayed) call
    if (tid < NB_PROD)
        pub_store64(&slab[tid], 0ull);
}

extern "C" void kernel_launch(void* const* d_in, const int* in_sizes, int n_in,
                              void* d_out, int out_size, void* d_ws, size_t ws_size,
                              hipStream_t stream) {
    const float* h0    = (const float*)d_in[0];
    const float* h1    = (const float*)d_in[1];
    const float* h2    = (const float*)d_in[2];
    const float* h3    = (const float*)d_in[3];
    const float* h4    = (const float*)d_in[4];
    const float* boxes = (const float*)d_in[5];
    const int*   dimx  = (const int*)d_in[6];
    const int*   dimy  = (const int*)d_in[7];
    unsigned long long* slab = (unsigned long long*)d_ws;
    float* out = (float*)d_out;

    k_fused<<<NB_TOTAL, THREADS, 0, stream>>>(h0, h1, h2, h3, h4, boxes,
                                              dimx, dimy, slab, out);
}

// Round 10
// 11.081 us; speedup vs baseline: 2.4258x; 1.0229x over previous
//
#include <hip/hip_runtime.h>

// ---------------------------------------------------------------------------
// Lamm loss on MI355X — ONE kernel node; 1024-thread blocks; fine y-bands;
// dedicated work-free combiner; register-prefetched box loads; fixup pass
// folded into the column scan (seg offset added inline, broadcast reads).
// Blocks [0,171): h-level partial sums (shuffle-reduced, deterministic).
// Blocks [171,187): raster bands: L0 x8, L1 x4, L2 x2, L3, L4 (producers).
// Block 187: combiner only — spins on slots from the start, joins, resets.
// Publish: ONE 8-byte relaxed agent-scope atomic store {flag=1 | payload}
//   (poison 0xAA != 1 => safe; combiner resets slots for next graph replay).
// ---------------------------------------------------------------------------

#define NBOXES   4096
#define NB_SUM   171
#define NB_PROD  187
#define NB_TOTAL 188
#define THREADS  1024
#define BPT      4               // boxes per thread = NBOXES / THREADS

__device__ __constant__ int c_LH[5] = {100, 50, 25, 13, 7};
__device__ __constant__ int c_LW[5] = {167, 84, 42, 21, 11};
__device__ __constant__ int c_LS[5] = {167, 85, 43, 21, 11};   // odd LDS stride
__device__ __constant__ int c_LN4[5] = {267200, 67200, 16800, 4368, 1232}; // 64*h*w/4

// raster band tables: L0 x8, L1 x4, L2 x2, L3, L4
__device__ __constant__ int c_RLVL[16] = {0,0,0,0,0,0,0,0, 1,1,1,1, 2,2, 3, 4};
__device__ __constant__ int c_RY0 [16] = {0,13,26,39,52,64,76,88, 0,13,26,38, 0,13, 0, 0};
__device__ __constant__ int c_RBH [16] = {13,13,13,13,12,12,12,12, 13,13,12,12, 13,12, 13, 7};

__device__ __forceinline__ void pub_store64(unsigned long long* p, unsigned long long v) {
    __hip_atomic_store(p, v, __ATOMIC_RELAXED, __HIP_MEMORY_SCOPE_AGENT);
}
__device__ __forceinline__ unsigned long long pub_load64(const unsigned long long* p) {
    return __hip_atomic_load(p, __ATOMIC_RELAXED, __HIP_MEMORY_SCOPE_AGENT);
}

__device__ __forceinline__ float wred_f(float s) {
    #pragma unroll
    for (int o = 32; o > 0; o >>= 1) s += __shfl_down(s, o, 64);
    return s;   // valid in lane 0
}
__device__ __forceinline__ int wred_i(int s) {
    #pragma unroll
    for (int o = 32; o > 0; o >>= 1) s += __shfl_down(s, o, 64);
    return s;   // valid in lane 0
}

__global__ __launch_bounds__(THREADS) void k_fused(
    const float* __restrict__ h0, const float* __restrict__ h1,
    const float* __restrict__ h2, const float* __restrict__ h3,
    const float* __restrict__ h4, const float* __restrict__ boxes,
    const int* __restrict__ dimx, const int* __restrict__ dimy,
    unsigned long long* __restrict__ slab, float* __restrict__ out)
{
    __shared__ int   sgrid[2172];    // max band grid 13*167 = 2171 (pad x4)
    __shared__ int   tot[112];       // row-scan segment totals -> prefixes
    __shared__ float w16f[16];
    __shared__ int   w16i[16];
    __shared__ int   lsum[5];        // fixed-point level h-sums (x256)
    __shared__ int   lcov[5];        // integer level coverage counts

    const int bid = blockIdx.x;
    const int tid = threadIdx.x;

    float myPartial = 0.0f;          // value this block publishes

    if (bid < NB_SUM) {
        // ------------------ h-level sum reduction ------------------
        int level;
        if      (bid < 128) level = 0;
        else if (bid < 160) level = 1;
        else if (bid < 168) level = 2;
        else if (bid < 170) level = 3;
        else                level = 4;

        const float* hp = (level == 0) ? h0 :
                          (level == 1) ? h1 :
                          (level == 2) ? h2 :
                          (level == 3) ? h3 : h4;
        const int n4   = c_LN4[level];
        const int nb   = (level==0)?128:(level==1)?32:(level==2)?8:(level==3)?2:1;
        const int boff = (level==0)?0:(level==1)?128:(level==2)?160:(level==3)?168:170;

        const float4* p = (const float4*)hp;
        int idx    = (bid - boff) * THREADS + tid;
        int stride = nb * THREADS;
        float s = 0.0f;
        for (int i = idx; i < n4; i += stride) {
            float4 v = p[i];
            s += v.x + v.y + v.z + v.w;
        }
        float r = wred_f(s);
        if ((tid & 63) == 0) w16f[tid >> 6] = r;
        __syncthreads();
        if (tid == 0) {
            float a = 0.0f;
            #pragma unroll
            for (int k = 0; k < 16; ++k) a += w16f[k];
            myPartial = a;
        }
    } else if (bid < NB_PROD) {
        // ------------------ raster band ------------------
        const int rb    = bid - NB_SUM;
        const int level = c_RLVL[rb];
        const int h  = c_LH[level];
        const int w  = c_LW[level];
        const int S  = c_LS[level];
        const int y0 = c_RY0[rb];
        const int bh = c_RBH[rb];
        const int cells = bh * S;

        // issue box loads + dim loads FIRST (latency hides under LDS zero)
        const float4* bx = (const float4*)boxes;
        float4 bv[BPT];
        #pragma unroll
        for (int k = 0; k < BPT; ++k) bv[k] = bx[tid + k * THREADS];
        const int dx = dimx[0], dy = dimy[0];

        // zero grid while loads are in flight
        int4* g4 = (int4*)sgrid;
        const int nz4 = (cells + 3) >> 2;
        for (int i = tid; i < nz4; i += THREADS) g4[i] = make_int4(0, 0, 0, 0);

        const float sx = (float)((double)w / (double)dx);
        const float sy = (float)((double)h / (double)dy);
        __syncthreads();

        #pragma unroll
        for (int k = 0; k < BPT; ++k) {
            float4 v = bv[k];
            // round (half-even = jnp.round) THEN clip, full-level coords
            int x1 = (int)fminf(fmaxf(rintf(v.x * sx), 0.0f), (float)(w - 1));
            int y1 = (int)fminf(fmaxf(rintf(v.y * sy), 0.0f), (float)(h - 1));
            int x2 = (int)fminf(fmaxf(rintf(v.z * sx), 0.0f), (float)w);
            int y2 = (int)fminf(fmaxf(rintf(v.w * sy), 0.0f), (float)h);
            bool valid = (x2 > x1) && (y2 > y1) && (x1 + x2 < w) && (y1 + y2 < h);
            if (valid) {
                int r1 = max(y1, y0) - y0;
                int r2 = min(y2, y0 + bh) - y0;
                if (r1 < r2) {
                    atomicAdd(&sgrid[r1 * S + x1], 1);
                    if (x2 < w) atomicAdd(&sgrid[r1 * S + x2], -1);
                    if (r2 < bh) {
                        atomicAdd(&sgrid[r2 * S + x1], -1);
                        if (x2 < w) atomicAdd(&sgrid[r2 * S + x2], 1);
                    }
                }
            }
        }
        __syncthreads();

        // ---- segmented row scan: 8 segs/row; totals -> tot ----
        const int segw  = (w + 7) >> 3;
        const int ntask = bh << 3;
        if (tid < ntask) {
            const int row = tid >> 3, seg = tid & 7;
            const int xA = seg * segw;
            const int xB = min(w, xA + segw);
            const int base = row * S;
            int run = 0;
            int x = xA;
            for (; x + 8 <= xB; x += 8) {
                int r0=sgrid[base+x  ],r1=sgrid[base+x+1],r2=sgrid[base+x+2],r3=sgrid[base+x+3];
                int r4=sgrid[base+x+4],r5=sgrid[base+x+5],r6=sgrid[base+x+6],r7=sgrid[base+x+7];
                run+=r0; sgrid[base+x  ]=run; run+=r1; sgrid[base+x+1]=run;
                run+=r2; sgrid[base+x+2]=run; run+=r3; sgrid[base+x+3]=run;
                run+=r4; sgrid[base+x+4]=run; run+=r5; sgrid[base+x+5]=run;
                run+=r6; sgrid[base+x+6]=run; run+=r7; sgrid[base+x+7]=run;
            }
            for (; x + 4 <= xB; x += 4) {
                int r0=sgrid[base+x],r1=sgrid[base+x+1],r2=sgrid[base+x+2],r3=sgrid[base+x+3];
                run+=r0; sgrid[base+x  ]=run; run+=r1; sgrid[base+x+1]=run;
                run+=r2; sgrid[base+x+2]=run; run+=r3; sgrid[base+x+3]=run;
            }
            for (; x < xB; ++x) { run += sgrid[base+x]; sgrid[base+x] = run; }
            tot[tid] = run;
        }
        __syncthreads();
        if (tid < bh) {    // exclusive prefix of 8 seg totals, in place
            const int b8 = tid << 3;
            int t0=tot[b8],t1=tot[b8+1],t2=tot[b8+2],t3=tot[b8+3];
            int t4=tot[b8+4],t5=tot[b8+5],t6=tot[b8+6];
            tot[b8] = 0;
            tot[b8+1]=t0; t0+=t1;
            tot[b8+2]=t0; t0+=t2;
            tot[b8+3]=t0; t0+=t3;
            tot[b8+4]=t0; t0+=t4;
            tot[b8+5]=t0; t0+=t5;
            tot[b8+6]=t0; t0+=t6;
            tot[b8+7]=t0;
        }
        __syncthreads();

        // ---- column scan + count; seg offset folded in (broadcast reads) --
        int cover = 0;
        if (tid < w) {
            const int segx = tid / segw;          // fixed per column
            int run = 0;
            int y = 0;
            for (; y + 8 <= bh; y += 8) {
                int r[8], tp[8];
                #pragma unroll
                for (int k = 0; k < 8; ++k) r[k]  = sgrid[(y + k) * S + tid];
                #pragma unroll
                for (int k = 0; k < 8; ++k) tp[k] = tot[((y + k) << 3) + segx];
                #pragma unroll
                for (int k = 0; k < 8; ++k) { run += r[k] + tp[k]; cover += (run > 0); }
            }
            for (; y + 4 <= bh; y += 4) {
                int r[4], tp[4];
                #pragma unroll
                for (int k = 0; k < 4; ++k) r[k]  = sgrid[(y + k) * S + tid];
                #pragma unroll
                for (int k = 0; k < 4; ++k) tp[k] = tot[((y + k) << 3) + segx];
                #pragma unroll
                for (int k = 0; k < 4; ++k) { run += r[k] + tp[k]; cover += (run > 0); }
            }
            for (; y < bh; ++y) {
                run += sgrid[y * S + tid] + tot[(y << 3) + segx];
                cover += (run > 0);
            }
        }
        int rc = wred_i(cover);
        if ((tid & 63) == 0) w16i[tid >> 6] = rc;
        __syncthreads();
        if (tid == 0) {
            int c = 0;
            #pragma unroll
            for (int k = 0; k < 16; ++k) c += w16i[k];
            myPartial = (float)c;
        }
    }

    // ------------------ publish (producers): single packed atomic ----------
    if (bid < NB_PROD) {
        if (tid == 0)
            pub_store64(&slab[bid],
                        (1ull << 32) | (unsigned long long)__float_as_uint(myPartial));
        return;
    }

    // ------------------ combiner (block 187): spin + fixed-point combine ---
    if (tid < 5) { lsum[tid] = 0; lcov[tid] = 0; }
    __syncthreads();

    float pv = 0.0f;
    if (tid < NB_PROD) {
        unsigned long long v;
        while (((v = pub_load64(&slab[tid])) >> 32) != 1ull)
            __builtin_amdgcn_s_sleep(1);
        pv = __uint_as_float((unsigned int)(v & 0xffffffffull));
    }
    if (tid < 128) {
        // level-0 partials: wave pre-reduce, 2 LDS atomics total
        float r = wred_f(pv);
        if ((tid & 63) == 0) atomicAdd(&lsum[0], (int)lrintf(r * 256.0f));
    } else if (tid < NB_SUM) {
        const int lvl = (tid < 160) ? 1 : (tid < 168) ? 2 : (tid < 170) ? 3 : 4;
        atomicAdd(&lsum[lvl], (int)lrintf(pv * 256.0f));
    } else if (tid < NB_PROD) {
        atomicAdd(&lcov[c_RLVL[tid - NB_SUM]], (int)pv);
    }
    __syncthreads();

    if (tid == 0) {
        float l = 0.0f;
        #pragma unroll
        for (int lvl = 0; lvl < 5; ++lvl) {
            const float tn  = (float)(64 * c_LH[lvl] * c_LW[lvl]);
            const float s   = (float)lsum[lvl] * (1.0f / 256.0f);
            const float cov = (float)lcov[lvl];
            const float d   = s / tn - cov / tn;
            l += d * d;
        }
        out[0] = l * 0.2f;
    }

    // reset slots for the next (graph-replayed) call
    if (tid < NB_PROD)
        pub_store64(&slab[tid], 0ull);
}

extern "C" void kernel_launch(void* const* d_in, const int* in_sizes, int n_in,
                              void* d_out, int out_size, void* d_ws, size_t ws_size,
                              hipStream_t stream) {
    const float* h0    = (const float*)d_in[0];
    const float* h1    = (const float*)d_in[1];
    const float* h2    = (const float*)d_in[2];
    const float* h3    = (const float*)d_in[3];
    const float* h4    = (const float*)d_in[4];
    const float* boxes = (const float*)d_in[5];
    const int*   dimx  = (const int*)d_in[6];
    const int*   dimy  = (const int*)d_in[7];
    unsigned long long* slab = (unsigned long long*)d_ws;
    float* out = (float*)d_out;

    k_fused<<<NB_TOTAL, THREADS, 0, stream>>>(h0, h1, h2, h3, h4, boxes,
                                              dimx, dimy, slab, out);
}